// Round 6
// baseline (584.787 us; speedup 1.0000x reference)
//
#include <hip/hip_runtime.h>
#include <hip/hip_bf16.h>

#define S_LEN 2048
#define DMODEL 512
#define NHEAD 8
#define DKH 64
#define FFDIM 2048
#define BATCH 2
#define NROWS (BATCH * S_LEN)  // 4096

using bf16 = __hip_bfloat16;
typedef __bf16 bf16x8 __attribute__((ext_vector_type(8)));
typedef float floatx4 __attribute__((ext_vector_type(4)));
typedef float floatx16 __attribute__((ext_vector_type(16)));

// fp32 -> bf16 round-to-nearest-even, branch-free
__device__ inline unsigned short f2bf_bits(float f) {
    union { float f; unsigned u; } c; c.f = f;
    return (unsigned short)((c.u + 0x7FFFu + ((c.u >> 16) & 1u)) >> 16);
}
__device__ inline unsigned pack2bf(float a, float b) {
    return (unsigned)f2bf_bits(a) | ((unsigned)f2bf_bits(b) << 16);
}

// async global->LDS, 16 bytes/lane. LDS dest is wave-uniform base + lane*16.
__device__ __forceinline__ void gload_lds16(const bf16* g, bf16* l) {
    __builtin_amdgcn_global_load_lds(
        (const __attribute__((address_space(1))) void*)(const void*)g,
        (__attribute__((address_space(3))) void*)(void*)l, 16, 0, 0);
}

// ---------------------------------------------------------------------------
// fp32 -> bf16 bulk convert, up to 12 segments in one dispatch.
// ---------------------------------------------------------------------------
struct CvtSeg { const float* s; bf16* d; int n4; };
struct CvtDesc { CvtSeg seg[12]; };

__launch_bounds__(256)
__global__ void cvt_f32_bf16(CvtDesc desc) {
    const CvtSeg sg = desc.seg[blockIdx.y];
    const int stride = gridDim.x * 256;
    for (int i = blockIdx.x * 256 + threadIdx.x; i < sg.n4; i += stride) {
        const float4 v = ((const float4*)sg.s)[i];
        uint2 o;
        o.x = pack2bf(v.x, v.y);
        o.y = pack2bf(v.z, v.w);
        ((uint2*)sg.d)[i] = o;
    }
}

// ---------------------------------------------------------------------------
// m97-style GEMM: C[M,N] = A[M,K] @ W[N,K]^T + bias. A,W bf16; bias fp32.
// QSCALE multiplies the result by 1/8 (folds attention's 1/sqrt(dk) into the
// Q projection). BMxBN tile, BK=32, 4 waves, global_load_lds staging.
// ---------------------------------------------------------------------------
template <int BM, int BN, bool RELU, bool QSCALE>
__launch_bounds__(256)
__global__ void gemm_lds(const bf16* __restrict__ A, const bf16* __restrict__ W,
                         const float* __restrict__ bias,
                         float* __restrict__ outF, bf16* __restrict__ outB,
                         int N, int K)
{
    constexpr int WR = BM / 32;
    constexpr int WC = BN / 32;
    constexpr int SA = BM / 16;
    constexpr int ST = SA + BN / 16;

    __shared__ alignas(16) bf16 As[BM * 32];
    __shared__ alignas(16) bf16 Bs[BN * 32];

    const int t = threadIdx.x;
    const int w = t >> 6;
    const int lane = t & 63;
    const int r16 = lane & 15;
    const int quad = lane >> 4;
    const int wm = w >> 1, wn = w & 1;
    const int m0 = blockIdx.x * BM;
    const int n0 = blockIdx.y * BN;

    floatx4 acc[WR][WC];
#pragma unroll
    for (int i = 0; i < WR; i++)
#pragma unroll
        for (int j = 0; j < WC; j++)
#pragma unroll
            for (int e = 0; e < 4; e++) acc[i][j][e] = 0.0f;

    const int srow = lane >> 2;
    const int scol = (lane & 3) * 8;

    const bf16* aLd = As + (size_t)((wm * (BM / 2)) + r16) * 32 + quad * 8;
    const bf16* bLd = Bs + (size_t)((wn * (BN / 2)) + r16) * 32 + quad * 8;

    for (int k0 = 0; k0 < K; k0 += 32) {
        __syncthreads();
#pragma unroll
        for (int s = 0; s < ST; s += 4) {
            const int sg = s + w;
            if (sg < ST) {
                const bf16* src = (sg < SA)
                    ? (A + ((size_t)(m0 + 16 * sg)) * K)
                    : (W + ((size_t)(n0 + 16 * (sg - SA))) * K);
                bf16* dst = (sg < SA) ? (As + sg * 16 * 32)
                                      : (Bs + (sg - SA) * 16 * 32);
                gload_lds16(src + (size_t)srow * K + k0 + scol, dst + lane * 8);
            }
        }
        __syncthreads();

        bf16x8 af[WR], bfr[WC];
#pragma unroll
        for (int i = 0; i < WR; i++)
            af[i] = *(const bf16x8*)(aLd + i * 16 * 32);
#pragma unroll
        for (int j = 0; j < WC; j++)
            bfr[j] = *(const bf16x8*)(bLd + j * 16 * 32);
#pragma unroll
        for (int i = 0; i < WR; i++)
#pragma unroll
            for (int j = 0; j < WC; j++)
                acc[i][j] = __builtin_amdgcn_mfma_f32_16x16x32_bf16(af[i], bfr[j], acc[i][j], 0, 0, 0);
    }

#pragma unroll
    for (int j = 0; j < WC; j++) {
        const int col = n0 + wn * (BN / 2) + 16 * j + r16;
        const float bv = bias ? bias[col] : 0.0f;
#pragma unroll
        for (int i = 0; i < WR; i++) {
            const int rowb = m0 + wm * (BM / 2) + 16 * i + 4 * quad;
#pragma unroll
            for (int e = 0; e < 4; e++) {
                float v = acc[i][j][e] + bv;
                if (RELU) v = fmaxf(v, 0.0f);
                if (QSCALE) v *= 0.125f;
                const size_t idx = (size_t)(rowb + e) * N + col;
                if (outF) outF[idx] = v;
                if (outB) outB[idx] = __float2bfloat16(v);
            }
        }
    }
}

// ---------------------------------------------------------------------------
// Flash attention on 32x32x16 MFMA. WG = 128 thr (2 waves); wave w owns
// queries q0+32w..+31 over full 64-key chunks. Q pre-scaled by 1/8 in the
// projection GEMM.
//  - S^T = K.Q^T: A = K direct from global/L2 (identical frags across waves;
//    no LDS staging), B = Q persistent regs. C/D (m74/m101-verified):
//    col(lane&31)=query, row=(reg&3)+8*(reg>>2)+4*(lane>>5)=key -> softmax
//    stats lane-resident, one shfl_xor(32) per reduction.
//  - V staged transposed in LDS via packed b64 writes (lanes stride 8B ->
//    conflict-free); PV B-frags are contiguous b128 rows of Vt.
//  - P: per-wave LDS region, b64 packed writes (C-layout) -> b128 A-frag reads.
// ---------------------------------------------------------------------------
#define PST 72  // LDS row stride (bf16): 64 + 8, keeps b128 alignment

__launch_bounds__(128)
__global__ void attn_mfma(const bf16* __restrict__ Qh, const bf16* __restrict__ Kh,
                          const bf16* __restrict__ Vh,
                          float* __restrict__ outF, bf16* __restrict__ outB,
                          int causal)
{
    __shared__ alignas(16) bf16 Vt[64][PST];      // [d][key]
    __shared__ alignas(16) bf16 Ps[2][32][PST];   // per-wave [q][key]

    const int t = threadIdx.x;        // 0..127
    const int w = t >> 6;
    const int lane = t & 63;
    const int c32 = lane & 31;
    const int hi = lane >> 5;
    const int bh = blockIdx.y;
    const int b = bh >> 3, h = bh & 7;
    const int q0 = blockIdx.x * 64;
    const size_t rowbase = (size_t)b * S_LEN;
    const int hoff = h * DKH;

    // persistent Q B-frags: lane holds Q[q=c32][d=16t+8hi+j]
    bf16x8 qf[4];
    {
        const bf16* qp = Qh + (rowbase + q0 + 32 * w + c32) * DMODEL + hoff + 8 * hi;
#pragma unroll
        for (int tt = 0; tt < 4; tt++) qf[tt] = *(const bf16x8*)(qp + 16 * tt);
    }

    floatx16 o0, o1;
#pragma unroll
    for (int e = 0; e < 16; e++) { o0[e] = 0.0f; o1[e] = 0.0f; }
    float m = -3e38f, l = 0.0f;

    // Vt staging: thread covers V rows 4rq..4rq+3, cols c8..c8+7
    const int rq = t & 15;
    const int c8 = ((t >> 4) & 7) * 8;

    const int nchunk = causal ? (q0 / 64 + 1) : (S_LEN / 64);

    for (int ch = 0; ch < nchunk; ch++) {
        const int kb = ch * 64;
        __syncthreads();   // all waves done reading Vt of previous chunk
        {   // stage V transposed: 4 rows x 8 cols -> 8 packed b64 writes
            union { uint4 u; unsigned short s[8]; } r0, r1, r2, r3;
            const bf16* vb = Vh + (rowbase + kb + 4 * rq) * DMODEL + hoff + c8;
            r0.u = *(const uint4*)(vb);
            r1.u = *(const uint4*)(vb + DMODEL);
            r2.u = *(const uint4*)(vb + 2 * DMODEL);
            r3.u = *(const uint4*)(vb + 3 * DMODEL);
#pragma unroll
            for (int j = 0; j < 8; j++) {
                ushort4 pk = { r0.s[j], r1.s[j], r2.s[j], r3.s[j] };
                *(ushort4*)&Vt[c8 + j][4 * rq] = pk;
            }
        }

        // ---- S^T = K . Q^T (A-frags straight from L2) ----
        floatx16 s0, s1;
#pragma unroll
        for (int e = 0; e < 16; e++) { s0[e] = 0.0f; s1[e] = 0.0f; }
        const bf16* kp = Kh + (rowbase + kb + c32) * DMODEL + hoff + 8 * hi;
#pragma unroll
        for (int tt = 0; tt < 4; tt++) {
            const bf16x8 k0 = *(const bf16x8*)(kp + 16 * tt);
            const bf16x8 k1 = *(const bf16x8*)(kp + (size_t)32 * DMODEL + 16 * tt);
            s0 = __builtin_amdgcn_mfma_f32_32x32x16_bf16(k0, qf[tt], s0, 0, 0, 0);
            s1 = __builtin_amdgcn_mfma_f32_32x32x16_bf16(k1, qf[tt], s1, 0, 0, 0);
        }

        // ---- causal mask (diagonal chunk only) ----
        if (causal && kb == q0) {
            const int qg = 32 * w + c32;   // query index within this 64-tile
#pragma unroll
            for (int r = 0; r < 16; r++) {
                const int kl = (r & 3) + 8 * (r >> 2) + 4 * hi;
                if (kl > qg) s0[r] = -3e38f;
                if (kl + 32 > qg) s1[r] = -3e38f;
            }
        }

        // ---- online softmax (stats per query = per lane) ----
        float mc = -3e38f;
#pragma unroll
        for (int r = 0; r < 16; r++) mc = fmaxf(mc, fmaxf(s0[r], s1[r]));
        mc = fmaxf(mc, __shfl_xor(mc, 32, 64));
        const float mn = fmaxf(m, mc);
        const float alpha = __expf(m - mn);
        m = mn;

        float lc = 0.0f;
#pragma unroll
        for (int g = 0; g < 4; g++) {
            float p0 = __expf(s0[4 * g + 0] - mn), p1 = __expf(s0[4 * g + 1] - mn);
            float p2 = __expf(s0[4 * g + 2] - mn), p3 = __expf(s0[4 * g + 3] - mn);
            lc += (p0 + p1) + (p2 + p3);
            ushort4 pk = { f2bf_bits(p0), f2bf_bits(p1), f2bf_bits(p2), f2bf_bits(p3) };
            *(ushort4*)&Ps[w][c32][8 * g + 4 * hi] = pk;
            p0 = __expf(s1[4 * g + 0] - mn); p1 = __expf(s1[4 * g + 1] - mn);
            p2 = __expf(s1[4 * g + 2] - mn); p3 = __expf(s1[4 * g + 3] - mn);
            lc += (p0 + p1) + (p2 + p3);
            ushort4 pk1 = { f2bf_bits(p0), f2bf_bits(p1), f2bf_bits(p2), f2bf_bits(p3) };
            *(ushort4*)&Ps[w][c32][32 + 8 * g + 4 * hi] = pk1;
        }
        lc += __shfl_xor(lc, 32, 64);
        l = l * alpha + lc;

        // ---- rescale O rows by alpha of their query ----
#pragma unroll
        for (int r = 0; r < 16; r++) {
            const float a = __shfl(alpha, (r & 3) + 8 * (r >> 2) + 4 * hi, 64);
            o0[r] *= a; o1[r] *= a;
        }

        __syncthreads();   // Vt staged

        // ---- O += P . V ----
#pragma unroll
        for (int tt = 0; tt < 4; tt++) {
            const bf16x8 pf = *(const bf16x8*)&Ps[w][c32][16 * tt + 8 * hi];
            const bf16x8 v0 = *(const bf16x8*)&Vt[c32][16 * tt + 8 * hi];
            const bf16x8 v1 = *(const bf16x8*)&Vt[32 + c32][16 * tt + 8 * hi];
            o0 = __builtin_amdgcn_mfma_f32_32x32x16_bf16(pf, v0, o0, 0, 0, 0);
            o1 = __builtin_amdgcn_mfma_f32_32x32x16_bf16(pf, v1, o1, 0, 0, 0);
        }
    }

    // ---- finalize ----
#pragma unroll
    for (int r = 0; r < 16; r++) {
        const int ql = (r & 3) + 8 * (r >> 2) + 4 * hi;
        const float li = 1.0f / __shfl(l, ql, 64);
        const size_t idx = (rowbase + q0 + 32 * w + ql) * DMODEL + hoff + c32;
        const float v0 = o0[r] * li, v1 = o1[r] * li;
        if (outF) { outF[idx] = v0; outF[idx + 32] = v1; }
        if (outB) { outB[idx] = __float2bfloat16(v0); outB[idx + 32] = __float2bfloat16(v1); }
    }
}

// ---------------------------------------------------------------------------
// Fused residual + LayerNorm over D=512. One WG (256 thr) per row.
// ---------------------------------------------------------------------------
__launch_bounds__(256)
__global__ void ln_kernel(const float* __restrict__ xmain,
                          const float* __restrict__ resF, const bf16* __restrict__ resB,
                          const float* __restrict__ g, const float* __restrict__ bb,
                          float* __restrict__ outF, bf16* __restrict__ outB)
{
    const int row = blockIdx.x;
    const int t = threadIdx.x;
    const size_t base = (size_t)row * DMODEL;

    float x0 = xmain[base + t];
    float x1 = xmain[base + t + 256];
    if (resF) { x0 += resF[base + t]; x1 += resF[base + t + 256]; }
    if (resB) { x0 += __bfloat162float(resB[base + t]); x1 += __bfloat162float(resB[base + t + 256]); }

    __shared__ float sred[4];
    float s = x0 + x1;
#pragma unroll
    for (int off = 32; off > 0; off >>= 1) s += __shfl_down(s, off);
    if ((t & 63) == 0) sred[t >> 6] = s;
    __syncthreads();
    const float mu = (sred[0] + sred[1] + sred[2] + sred[3]) * (1.0f / DMODEL);

    const float d0 = x0 - mu, d1 = x1 - mu;
    float sv = d0 * d0 + d1 * d1;
#pragma unroll
    for (int off = 32; off > 0; off >>= 1) sv += __shfl_down(sv, off);
    __syncthreads();
    if ((t & 63) == 0) sred[t >> 6] = sv;
    __syncthreads();
    const float var = (sred[0] + sred[1] + sred[2] + sred[3]) * (1.0f / DMODEL);
    const float rstd = rsqrtf(var + 1e-5f);

    const float y0 = d0 * rstd * g[t] + bb[t];
    const float y1 = d1 * rstd * g[t + 256] + bb[t + 256];
    if (outF) { outF[base + t] = y0; outF[base + t + 256] = y1; }
    if (outB) { outB[base + t] = __float2bfloat16(y0); outB[base + t + 256] = __float2bfloat16(y1); }
}

// ---------------------------------------------------------------------------
// Workspace layout (55.5 MB) — see round 5 comment.
// ---------------------------------------------------------------------------
extern "C" void kernel_launch(void* const* d_in, const int* in_sizes, int n_in,
                              void* d_out, int out_size, void* d_ws, size_t ws_size,
                              hipStream_t stream)
{
    const float* x_q       = (const float*)d_in[0];
    const float* x1        = (const float*)d_in[1];
    const float* x2        = (const float*)d_in[2];
    const float* sa_wq     = (const float*)d_in[3];
    const float* sa_bq     = (const float*)d_in[4];
    const float* sa_wk     = (const float*)d_in[5];
    const float* sa_bk     = (const float*)d_in[6];
    const float* sa_wv     = (const float*)d_in[7];
    const float* sa_bv     = (const float*)d_in[8];
    const float* ln1_g     = (const float*)d_in[9];
    const float* ln1_b     = (const float*)d_in[10];
    const float* mha_in_w  = (const float*)d_in[11];
    const float* mha_in_b  = (const float*)d_in[12];
    const float* mha_out_w = (const float*)d_in[13];
    const float* mha_out_b = (const float*)d_in[14];
    const float* ln2_g     = (const float*)d_in[15];
    const float* ln2_b     = (const float*)d_in[16];
    const float* ffn_w1    = (const float*)d_in[17];
    const float* ffn_b1    = (const float*)d_in[18];
    const float* ffn_w2    = (const float*)d_in[19];
    const float* ffn_b2    = (const float*)d_in[20];
    const float* ln3_g     = (const float*)d_in[21];
    const float* ln3_b     = (const float*)d_in[22];

    char* ws = (char*)d_ws;
    const size_t MB = 1024 * 1024;
    const size_t KB = 1024;
    bf16*  q16  = (bf16*)(ws + 0 * MB);
    bf16*  k16  = (bf16*)(ws + 4 * MB);
    bf16*  v16  = (bf16*)(ws + 8 * MB);
    bf16*  a16  = (bf16*)(ws + 12 * MB);
    float* tmp  = (float*)(ws + 16 * MB);
    bf16*  y16  = (bf16*)(ws + 24 * MB);
    bf16*  ya16 = (bf16*)(ws + 28 * MB);
    bf16*  ya2  = (bf16*)(ws + 32 * MB);
    bf16*  xq16 = (bf16*)(ws + 36 * MB);
    bf16*  x116 = (bf16*)(ws + 40 * MB);
    bf16*  x216 = (bf16*)(ws + 44 * MB);
    bf16*  w_sa_q = (bf16*)(ws + 48 * MB);
    bf16*  w_sa_k = (bf16*)(ws + 48 * MB + 512 * KB);
    bf16*  w_sa_v = (bf16*)(ws + 49 * MB);
    bf16*  w_in   = (bf16*)(ws + 49 * MB + 512 * KB);
    bf16*  w_out  = (bf16*)(ws + 51 * MB);
    bf16*  w_f1   = (bf16*)(ws + 51 * MB + 512 * KB);
    bf16*  w_f2   = (bf16*)(ws + 53 * MB + 512 * KB);
    bf16*  h16    = (bf16*)(ws + 0 * MB);

    const int DD = DMODEL * DMODEL;
    CvtDesc cd;
    cd.seg[0]  = { x_q,       xq16,   (NROWS * DMODEL) / 4 };
    cd.seg[1]  = { x1,        x116,   (NROWS * DMODEL) / 4 };
    cd.seg[2]  = { x2,        x216,   (NROWS * DMODEL) / 4 };
    cd.seg[3]  = { sa_wq,     w_sa_q, DD / 4 };
    cd.seg[4]  = { sa_wk,     w_sa_k, DD / 4 };
    cd.seg[5]  = { sa_wv,     w_sa_v, DD / 4 };
    cd.seg[6]  = { mha_in_w,  w_in,   3 * DD / 4 };
    cd.seg[7]  = { mha_out_w, w_out,  DD / 4 };
    cd.seg[8]  = { ffn_w1,    w_f1,   (FFDIM * DMODEL) / 4 };
    cd.seg[9]  = { ffn_w2,    w_f2,   (FFDIM * DMODEL) / 4 };
    cd.seg[10] = { x_q,       xq16,   0 };
    cd.seg[11] = { x_q,       xq16,   0 };
    cvt_f32_bf16<<<dim3(64, 10), 256, 0, stream>>>(cd);

    const dim3 blk(256);
    const dim3 ablk(128);
    const dim3 g512(NROWS / 128, DMODEL / 64);   // 256 blocks
    const dim3 gFF1(NROWS / 128, FFDIM / 128);   // 512 blocks
    const dim3 agrid(S_LEN / 64, BATCH * NHEAD); // (32,16) = 512 WGs

    // ---- self attention (causal, no out-proj) ----
    gemm_lds<128, 64, false, true ><<<g512, blk, 0, stream>>>(xq16, w_sa_q, sa_bq, nullptr, q16, DMODEL, DMODEL);
    gemm_lds<128, 64, false, false><<<g512, blk, 0, stream>>>(xq16, w_sa_k, sa_bk, nullptr, k16, DMODEL, DMODEL);
    gemm_lds<128, 64, false, false><<<g512, blk, 0, stream>>>(xq16, w_sa_v, sa_bv, nullptr, v16, DMODEL, DMODEL);
    attn_mfma<<<agrid, ablk, 0, stream>>>(q16, k16, v16, tmp, nullptr, 1);
    ln_kernel<<<NROWS, blk, 0, stream>>>(tmp, x_q, nullptr, ln1_g, ln1_b, nullptr, y16);

    // ---- cross attention 1: q from y, k/v from x1 ----
    gemm_lds<128, 64, false, true ><<<g512, blk, 0, stream>>>(y16, w_in, mha_in_b, nullptr, q16, DMODEL, DMODEL);
    gemm_lds<128, 64, false, false><<<g512, blk, 0, stream>>>(x116, w_in + (size_t)DD, mha_in_b + DMODEL, nullptr, k16, DMODEL, DMODEL);
    gemm_lds<128, 64, false, false><<<g512, blk, 0, stream>>>(x116, w_in + (size_t)2 * DD, mha_in_b + 2 * DMODEL, nullptr, v16, DMODEL, DMODEL);
    attn_mfma<<<agrid, ablk, 0, stream>>>(q16, k16, v16, nullptr, a16, 0);
    gemm_lds<128, 64, false, false><<<g512, blk, 0, stream>>>(a16, w_out, mha_out_b, tmp, nullptr, DMODEL, DMODEL);
    ln_kernel<<<NROWS, blk, 0, stream>>>(tmp, nullptr, y16, ln2_g, ln2_b, nullptr, ya16);

    // ---- cross attention 2: q from yattn, k/v from x2 ----
    gemm_lds<128, 64, false, true ><<<g512, blk, 0, stream>>>(ya16, w_in, mha_in_b, nullptr, q16, DMODEL, DMODEL);
    gemm_lds<128, 64, false, false><<<g512, blk, 0, stream>>>(x216, w_in + (size_t)DD, mha_in_b + DMODEL, nullptr, k16, DMODEL, DMODEL);
    gemm_lds<128, 64, false, false><<<g512, blk, 0, stream>>>(x216, w_in + (size_t)2 * DD, mha_in_b + 2 * DMODEL, nullptr, v16, DMODEL, DMODEL);
    attn_mfma<<<agrid, ablk, 0, stream>>>(q16, k16, v16, nullptr, a16, 0);
    gemm_lds<128, 64, false, false><<<g512, blk, 0, stream>>>(a16, w_out, mha_out_b, tmp, nullptr, DMODEL, DMODEL);
    ln_kernel<<<NROWS, blk, 0, stream>>>(tmp, nullptr, ya16, ln2_g, ln2_b, nullptr, ya2);

    // ---- FFN ----
    gemm_lds<128, 128, true , false><<<gFF1, blk, 0, stream>>>(ya2, w_f1, ffn_b1, nullptr, h16, FFDIM, DMODEL);
    gemm_lds<128, 64, false, false><<<g512, blk, 0, stream>>>(h16, w_f2, ffn_b2, tmp, nullptr, DMODEL, FFDIM);
    ln_kernel<<<NROWS, blk, 0, stream>>>(tmp, nullptr, ya2, ln3_g, ln3_b, (float*)d_out, nullptr);
}

// Round 7
// 477.984 us; speedup vs baseline: 1.2234x; 1.2234x over previous
//
#include <hip/hip_runtime.h>
#include <hip/hip_bf16.h>

#define S_LEN 2048
#define DMODEL 512
#define NHEAD 8
#define DKH 64
#define FFDIM 2048
#define BATCH 2
#define NROWS (BATCH * S_LEN)  // 4096

using bf16 = __hip_bfloat16;
typedef __bf16 bf16x8 __attribute__((ext_vector_type(8)));
typedef float floatx4 __attribute__((ext_vector_type(4)));
typedef float floatx16 __attribute__((ext_vector_type(16)));

// fp32 -> bf16 round-to-nearest-even, branch-free
__device__ inline unsigned short f2bf_bits(float f) {
    union { float f; unsigned u; } c; c.f = f;
    return (unsigned short)((c.u + 0x7FFFu + ((c.u >> 16) & 1u)) >> 16);
}
__device__ inline unsigned pack2bf(float a, float b) {
    return (unsigned)f2bf_bits(a) | ((unsigned)f2bf_bits(b) << 16);
}

// async global->LDS, 16 bytes/lane. LDS dest is wave-uniform base + lane*16.
__device__ __forceinline__ void gload_lds16(const bf16* g, bf16* l) {
    __builtin_amdgcn_global_load_lds(
        (const __attribute__((address_space(1))) void*)(const void*)g,
        (__attribute__((address_space(3))) void*)(void*)l, 16, 0, 0);
}

// ---------------------------------------------------------------------------
// fp32 -> bf16 bulk convert, up to 12 segments in one dispatch.
// ---------------------------------------------------------------------------
struct CvtSeg { const float* s; bf16* d; int n4; };
struct CvtDesc { CvtSeg seg[12]; };

__launch_bounds__(256)
__global__ void cvt_f32_bf16(CvtDesc desc) {
    const CvtSeg sg = desc.seg[blockIdx.y];
    const int stride = gridDim.x * 256;
    for (int i = blockIdx.x * 256 + threadIdx.x; i < sg.n4; i += stride) {
        const float4 v = ((const float4*)sg.s)[i];
        uint2 o;
        o.x = pack2bf(v.x, v.y);
        o.y = pack2bf(v.z, v.w);
        ((uint2*)sg.d)[i] = o;
    }
}

// ---------------------------------------------------------------------------
// m97-style GEMM: C[M,N] = A[M,K] @ W[N,K]^T + bias. A,W bf16; bias fp32.
// BM=BN=64 -> 512 blocks for the N=512 shapes (2 WG/CU, 2 waves/SIMD).
// QSCALE folds attention's 1/sqrt(dk) into the Q projection.
// ---------------------------------------------------------------------------
template <int BM, int BN, bool RELU, bool QSCALE>
__launch_bounds__(256)
__global__ void gemm_lds(const bf16* __restrict__ A, const bf16* __restrict__ W,
                         const float* __restrict__ bias,
                         float* __restrict__ outF, bf16* __restrict__ outB,
                         int N, int K)
{
    constexpr int WR = BM / 32;
    constexpr int WC = BN / 32;
    constexpr int SA = BM / 16;
    constexpr int ST = SA + BN / 16;

    __shared__ alignas(16) bf16 As[BM * 32];
    __shared__ alignas(16) bf16 Bs[BN * 32];

    const int t = threadIdx.x;
    const int w = t >> 6;
    const int lane = t & 63;
    const int r16 = lane & 15;
    const int quad = lane >> 4;
    const int wm = w >> 1, wn = w & 1;
    const int m0 = blockIdx.x * BM;
    const int n0 = blockIdx.y * BN;

    floatx4 acc[WR][WC];
#pragma unroll
    for (int i = 0; i < WR; i++)
#pragma unroll
        for (int j = 0; j < WC; j++)
#pragma unroll
            for (int e = 0; e < 4; e++) acc[i][j][e] = 0.0f;

    const int srow = lane >> 2;
    const int scol = (lane & 3) * 8;

    const bf16* aLd = As + (size_t)((wm * (BM / 2)) + r16) * 32 + quad * 8;
    const bf16* bLd = Bs + (size_t)((wn * (BN / 2)) + r16) * 32 + quad * 8;

    for (int k0 = 0; k0 < K; k0 += 32) {
        __syncthreads();
#pragma unroll
        for (int s = 0; s < ST; s += 4) {
            const int sg = s + w;
            if (sg < ST) {
                const bf16* src = (sg < SA)
                    ? (A + ((size_t)(m0 + 16 * sg)) * K)
                    : (W + ((size_t)(n0 + 16 * (sg - SA))) * K);
                bf16* dst = (sg < SA) ? (As + sg * 16 * 32)
                                      : (Bs + (sg - SA) * 16 * 32);
                gload_lds16(src + (size_t)srow * K + k0 + scol, dst + lane * 8);
            }
        }
        __syncthreads();

        bf16x8 af[WR], bfr[WC];
#pragma unroll
        for (int i = 0; i < WR; i++)
            af[i] = *(const bf16x8*)(aLd + i * 16 * 32);
#pragma unroll
        for (int j = 0; j < WC; j++)
            bfr[j] = *(const bf16x8*)(bLd + j * 16 * 32);
#pragma unroll
        for (int i = 0; i < WR; i++)
#pragma unroll
            for (int j = 0; j < WC; j++)
                acc[i][j] = __builtin_amdgcn_mfma_f32_16x16x32_bf16(af[i], bfr[j], acc[i][j], 0, 0, 0);
    }

#pragma unroll
    for (int j = 0; j < WC; j++) {
        const int col = n0 + wn * (BN / 2) + 16 * j + r16;
        const float bv = bias ? bias[col] : 0.0f;
#pragma unroll
        for (int i = 0; i < WR; i++) {
            const int rowb = m0 + wm * (BM / 2) + 16 * i + 4 * quad;
#pragma unroll
            for (int e = 0; e < 4; e++) {
                float v = acc[i][j][e] + bv;
                if (RELU) v = fmaxf(v, 0.0f);
                if (QSCALE) v *= 0.125f;
                const size_t idx = (size_t)(rowb + e) * N + col;
                if (outF) outF[idx] = v;
                if (outB) outB[idx] = __float2bfloat16(v);
            }
        }
    }
}

// ---------------------------------------------------------------------------
// Flash attention, 32x32x16 MFMA, key-split across wave-pairs.
// WG = 256 thr (4 waves) per (bh, 64-query tile).
//   qgroup = w&1  : which 32 queries of the tile this wave owns
//   pair   = w>>1 : which key-chunk subsequence (chunks 2*it+pair)
// Per-pair Vt staging; per-wave online softmax (stats lane-resident, query =
// lane&31; C/D row = (reg&3)+8*(reg>>2)+4*(lane>>5) per m74/m101); pair-1
// partials merged into pair-0 via LDS (split-KV merge) at the end.
// Q pre-scaled by 1/8 in the projection GEMM.
// ---------------------------------------------------------------------------
#define PST 72  // LDS row stride (bf16): 64 + 8, keeps b128 alignment

__launch_bounds__(256)
__global__ void attn_mfma(const bf16* __restrict__ Qh, const bf16* __restrict__ Kh,
                          const bf16* __restrict__ Vh,
                          float* __restrict__ outF, bf16* __restrict__ outB,
                          int causal)
{
    __shared__ alignas(16) bf16 Vt[2][64][PST];    // per-pair [d][key]
    __shared__ alignas(16) bf16 Ps[4][32][PST];    // per-wave [q][key]
    __shared__ float Msh[2][64][34];               // merge: [qgroup][lane][m,l,o0[16],o1[16]]

    const int t = threadIdx.x;        // 0..255
    const int w = t >> 6;
    const int lane = t & 63;
    const int c32 = lane & 31;
    const int hi = lane >> 5;
    const int pair = t >> 7;          // waves {0,1}=pair0, {2,3}=pair1
    const int qg = w & 1;
    const int pl = t & 127;           // pair-local thread id
    const int bh = blockIdx.y;
    const int b = bh >> 3, h = bh & 7;
    const int q0 = blockIdx.x * 64;
    const size_t rowbase = (size_t)b * S_LEN;
    const int hoff = h * DKH;

    // persistent Q B-frags: lane holds Q[q=c32][d=16t+8hi+j]
    bf16x8 qf[4];
    {
        const bf16* qp = Qh + (rowbase + q0 + 32 * qg + c32) * DMODEL + hoff + 8 * hi;
#pragma unroll
        for (int tt = 0; tt < 4; tt++) qf[tt] = *(const bf16x8*)(qp + 16 * tt);
    }

    floatx16 o0, o1;
#pragma unroll
    for (int e = 0; e < 16; e++) { o0[e] = 0.0f; o1[e] = 0.0f; }
    float m = -3e38f, l = 0.0f;

    // Vt staging (within pair): thread covers V rows 4rq..4rq+3, cols c8..c8+7
    const int rq = pl & 15;
    const int c8 = ((pl >> 4) & 7) * 8;

    const int nchunk = causal ? (q0 / 64 + 1) : (S_LEN / 64);
    const int nIter = (nchunk + 1) >> 1;

    for (int it = 0; it < nIter; it++) {
        const int ch = 2 * it + pair;
        const bool active = ch < nchunk;
        const int kb = ch * 64;
        __syncthreads();   // pair's waves done reading Vt of previous chunk
        if (active) {      // stage V transposed (packed b64 writes, conflict-free)
            union { uint4 u; unsigned short s[8]; } r0, r1, r2, r3;
            const bf16* vb = Vh + (rowbase + kb + 4 * rq) * DMODEL + hoff + c8;
            r0.u = *(const uint4*)(vb);
            r1.u = *(const uint4*)(vb + DMODEL);
            r2.u = *(const uint4*)(vb + 2 * DMODEL);
            r3.u = *(const uint4*)(vb + 3 * DMODEL);
#pragma unroll
            for (int j = 0; j < 8; j++) {
                ushort4 pk = { r0.s[j], r1.s[j], r2.s[j], r3.s[j] };
                *(ushort4*)&Vt[pair][c8 + j][4 * rq] = pk;
            }
        }

        if (active) {
            // ---- S^T = K . Q^T (A-frags straight from L2) ----
            floatx16 s0, s1;
#pragma unroll
            for (int e = 0; e < 16; e++) { s0[e] = 0.0f; s1[e] = 0.0f; }
            const bf16* kp = Kh + (rowbase + kb + c32) * DMODEL + hoff + 8 * hi;
#pragma unroll
            for (int tt = 0; tt < 4; tt++) {
                const bf16x8 k0 = *(const bf16x8*)(kp + 16 * tt);
                const bf16x8 k1 = *(const bf16x8*)(kp + (size_t)32 * DMODEL + 16 * tt);
                s0 = __builtin_amdgcn_mfma_f32_32x32x16_bf16(k0, qf[tt], s0, 0, 0, 0);
                s1 = __builtin_amdgcn_mfma_f32_32x32x16_bf16(k1, qf[tt], s1, 0, 0, 0);
            }

            // ---- causal mask (diagonal chunk only) ----
            if (causal && kb == q0) {
                const int qq = 32 * qg + c32;   // query index within the 64-tile
#pragma unroll
                for (int r = 0; r < 16; r++) {
                    const int kl = (r & 3) + 8 * (r >> 2) + 4 * hi;
                    if (kl > qq) s0[r] = -3e38f;
                    if (kl + 32 > qq) s1[r] = -3e38f;
                }
            }

            // ---- online softmax (stats per query = per lane) ----
            float mc = -3e38f;
#pragma unroll
            for (int r = 0; r < 16; r++) mc = fmaxf(mc, fmaxf(s0[r], s1[r]));
            mc = fmaxf(mc, __shfl_xor(mc, 32, 64));
            const float mn = fmaxf(m, mc);
            const float alpha = __expf(m - mn);
            m = mn;

            float lc = 0.0f;
#pragma unroll
            for (int g = 0; g < 4; g++) {
                float p0 = __expf(s0[4 * g + 0] - mn), p1 = __expf(s0[4 * g + 1] - mn);
                float p2 = __expf(s0[4 * g + 2] - mn), p3 = __expf(s0[4 * g + 3] - mn);
                lc += (p0 + p1) + (p2 + p3);
                ushort4 pk = { f2bf_bits(p0), f2bf_bits(p1), f2bf_bits(p2), f2bf_bits(p3) };
                *(ushort4*)&Ps[w][c32][8 * g + 4 * hi] = pk;
                p0 = __expf(s1[4 * g + 0] - mn); p1 = __expf(s1[4 * g + 1] - mn);
                p2 = __expf(s1[4 * g + 2] - mn); p3 = __expf(s1[4 * g + 3] - mn);
                lc += (p0 + p1) + (p2 + p3);
                ushort4 pk1 = { f2bf_bits(p0), f2bf_bits(p1), f2bf_bits(p2), f2bf_bits(p3) };
                *(ushort4*)&Ps[w][c32][32 + 8 * g + 4 * hi] = pk1;
            }
            lc += __shfl_xor(lc, 32, 64);
            l = l * alpha + lc;

            // ---- rescale O rows by alpha of their query ----
#pragma unroll
            for (int r = 0; r < 16; r++) {
                const float a = __shfl(alpha, (r & 3) + 8 * (r >> 2) + 4 * hi, 64);
                o0[r] *= a; o1[r] *= a;
            }
        }

        __syncthreads();   // Vt staged (and safe vs next overwrite)

        if (active) {
            // ---- O += P . V ----
#pragma unroll
            for (int tt = 0; tt < 4; tt++) {
                const bf16x8 pf = *(const bf16x8*)&Ps[w][c32][16 * tt + 8 * hi];
                const bf16x8 v0 = *(const bf16x8*)&Vt[pair][c32][16 * tt + 8 * hi];
                const bf16x8 v1 = *(const bf16x8*)&Vt[pair][32 + c32][16 * tt + 8 * hi];
                o0 = __builtin_amdgcn_mfma_f32_32x32x16_bf16(pf, v0, o0, 0, 0, 0);
                o1 = __builtin_amdgcn_mfma_f32_32x32x16_bf16(pf, v1, o1, 0, 0, 0);
            }
        }
    }

    // ---- split-KV merge: pair1 -> LDS, pair0 combines & writes ----
    __syncthreads();
    if (pair == 1) {
        float* dst = &Msh[qg][lane][0];
        dst[0] = m; dst[1] = l;
#pragma unroll
        for (int r = 0; r < 16; r++) { dst[2 + r] = o0[r]; dst[18 + r] = o1[r]; }
    }
    __syncthreads();
    if (pair == 0) {
        const float* src = &Msh[qg][lane][0];
        const float m_b = src[0], l_b = src[1];
        const float mt = fmaxf(m, m_b);
        const float sA = __expf(m - mt);
        const float sB = __expf(m_b - mt);
        const float lt = l * sA + l_b * sB;
#pragma unroll
        for (int r = 0; r < 16; r++) {
            const int ql = (r & 3) + 8 * (r >> 2) + 4 * hi;
            const float sAr = __shfl(sA, ql, 64);
            const float sBr = __shfl(sB, ql, 64);
            const float li = 1.0f / __shfl(lt, ql, 64);
            const float v0 = (o0[r] * sAr + src[2 + r] * sBr) * li;
            const float v1 = (o1[r] * sAr + src[18 + r] * sBr) * li;
            const size_t idx = (rowbase + q0 + 32 * qg + ql) * DMODEL + hoff + c32;
            if (outF) { outF[idx] = v0; outF[idx + 32] = v1; }
            if (outB) { outB[idx] = __float2bfloat16(v0); outB[idx + 32] = __float2bfloat16(v1); }
        }
    }
}

// ---------------------------------------------------------------------------
// Fused residual + LayerNorm over D=512. One WG (256 thr) per row.
// ---------------------------------------------------------------------------
__launch_bounds__(256)
__global__ void ln_kernel(const float* __restrict__ xmain,
                          const float* __restrict__ resF, const bf16* __restrict__ resB,
                          const float* __restrict__ g, const float* __restrict__ bb,
                          float* __restrict__ outF, bf16* __restrict__ outB)
{
    const int row = blockIdx.x;
    const int t = threadIdx.x;
    const size_t base = (size_t)row * DMODEL;

    float x0 = xmain[base + t];
    float x1 = xmain[base + t + 256];
    if (resF) { x0 += resF[base + t]; x1 += resF[base + t + 256]; }
    if (resB) { x0 += __bfloat162float(resB[base + t]); x1 += __bfloat162float(resB[base + t + 256]); }

    __shared__ float sred[4];
    float s = x0 + x1;
#pragma unroll
    for (int off = 32; off > 0; off >>= 1) s += __shfl_down(s, off);
    if ((t & 63) == 0) sred[t >> 6] = s;
    __syncthreads();
    const float mu = (sred[0] + sred[1] + sred[2] + sred[3]) * (1.0f / DMODEL);

    const float d0 = x0 - mu, d1 = x1 - mu;
    float sv = d0 * d0 + d1 * d1;
#pragma unroll
    for (int off = 32; off > 0; off >>= 1) sv += __shfl_down(sv, off);
    __syncthreads();
    if ((t & 63) == 0) sred[t >> 6] = sv;
    __syncthreads();
    const float var = (sred[0] + sred[1] + sred[2] + sred[3]) * (1.0f / DMODEL);
    const float rstd = rsqrtf(var + 1e-5f);

    const float y0 = d0 * rstd * g[t] + bb[t];
    const float y1 = d1 * rstd * g[t + 256] + bb[t + 256];
    if (outF) { outF[base + t] = y0; outF[base + t + 256] = y1; }
    if (outB) { outB[base + t] = __float2bfloat16(y0); outB[base + t + 256] = __float2bfloat16(y1); }
}

// ---------------------------------------------------------------------------
// Workspace layout (55.5 MB) — see round 5 comment.
// ---------------------------------------------------------------------------
extern "C" void kernel_launch(void* const* d_in, const int* in_sizes, int n_in,
                              void* d_out, int out_size, void* d_ws, size_t ws_size,
                              hipStream_t stream)
{
    const float* x_q       = (const float*)d_in[0];
    const float* x1        = (const float*)d_in[1];
    const float* x2        = (const float*)d_in[2];
    const float* sa_wq     = (const float*)d_in[3];
    const float* sa_bq     = (const float*)d_in[4];
    const float* sa_wk     = (const float*)d_in[5];
    const float* sa_bk     = (const float*)d_in[6];
    const float* sa_wv     = (const float*)d_in[7];
    const float* sa_bv     = (const float*)d_in[8];
    const float* ln1_g     = (const float*)d_in[9];
    const float* ln1_b     = (const float*)d_in[10];
    const float* mha_in_w  = (const float*)d_in[11];
    const float* mha_in_b  = (const float*)d_in[12];
    const float* mha_out_w = (const float*)d_in[13];
    const float* mha_out_b = (const float*)d_in[14];
    const float* ln2_g     = (const float*)d_in[15];
    const float* ln2_b     = (const float*)d_in[16];
    const float* ffn_w1    = (const float*)d_in[17];
    const float* ffn_b1    = (const float*)d_in[18];
    const float* ffn_w2    = (const float*)d_in[19];
    const float* ffn_b2    = (const float*)d_in[20];
    const float* ln3_g     = (const float*)d_in[21];
    const float* ln3_b     = (const float*)d_in[22];

    char* ws = (char*)d_ws;
    const size_t MB = 1024 * 1024;
    const size_t KB = 1024;
    bf16*  q16  = (bf16*)(ws + 0 * MB);
    bf16*  k16  = (bf16*)(ws + 4 * MB);
    bf16*  v16  = (bf16*)(ws + 8 * MB);
    bf16*  a16  = (bf16*)(ws + 12 * MB);
    float* tmp  = (float*)(ws + 16 * MB);
    bf16*  y16  = (bf16*)(ws + 24 * MB);
    bf16*  ya16 = (bf16*)(ws + 28 * MB);
    bf16*  ya2  = (bf16*)(ws + 32 * MB);
    bf16*  xq16 = (bf16*)(ws + 36 * MB);
    bf16*  x116 = (bf16*)(ws + 40 * MB);
    bf16*  x216 = (bf16*)(ws + 44 * MB);
    bf16*  w_sa_q = (bf16*)(ws + 48 * MB);
    bf16*  w_sa_k = (bf16*)(ws + 48 * MB + 512 * KB);
    bf16*  w_sa_v = (bf16*)(ws + 49 * MB);
    bf16*  w_in   = (bf16*)(ws + 49 * MB + 512 * KB);
    bf16*  w_out  = (bf16*)(ws + 51 * MB);
    bf16*  w_f1   = (bf16*)(ws + 51 * MB + 512 * KB);
    bf16*  w_f2   = (bf16*)(ws + 53 * MB + 512 * KB);
    bf16*  h16    = (bf16*)(ws + 0 * MB);

    const int DD = DMODEL * DMODEL;
    CvtDesc cd;
    cd.seg[0]  = { x_q,       xq16,   (NROWS * DMODEL) / 4 };
    cd.seg[1]  = { x1,        x116,   (NROWS * DMODEL) / 4 };
    cd.seg[2]  = { x2,        x216,   (NROWS * DMODEL) / 4 };
    cd.seg[3]  = { sa_wq,     w_sa_q, DD / 4 };
    cd.seg[4]  = { sa_wk,     w_sa_k, DD / 4 };
    cd.seg[5]  = { sa_wv,     w_sa_v, DD / 4 };
    cd.seg[6]  = { mha_in_w,  w_in,   3 * DD / 4 };
    cd.seg[7]  = { mha_out_w, w_out,  DD / 4 };
    cd.seg[8]  = { ffn_w1,    w_f1,   (FFDIM * DMODEL) / 4 };
    cd.seg[9]  = { ffn_w2,    w_f2,   (FFDIM * DMODEL) / 4 };
    cd.seg[10] = { x_q,       xq16,   0 };
    cd.seg[11] = { x_q,       xq16,   0 };
    cvt_f32_bf16<<<dim3(64, 10), 256, 0, stream>>>(cd);

    const dim3 blk(256);
    const dim3 g512(NROWS / 64, DMODEL / 64);    // (64,8) = 512 blocks, 64x64 tile
    const dim3 gFF1(NROWS / 128, FFDIM / 128);   // (32,16) = 512 blocks, 128x128
    const dim3 agrid(S_LEN / 64, BATCH * NHEAD); // (32,16) = 512 WGs, 4 waves

    // ---- self attention (causal, no out-proj) ----
    gemm_lds<64, 64, false, true ><<<g512, blk, 0, stream>>>(xq16, w_sa_q, sa_bq, nullptr, q16, DMODEL, DMODEL);
    gemm_lds<64, 64, false, false><<<g512, blk, 0, stream>>>(xq16, w_sa_k, sa_bk, nullptr, k16, DMODEL, DMODEL);
    gemm_lds<64, 64, false, false><<<g512, blk, 0, stream>>>(xq16, w_sa_v, sa_bv, nullptr, v16, DMODEL, DMODEL);
    attn_mfma<<<agrid, blk, 0, stream>>>(q16, k16, v16, tmp, nullptr, 1);
    ln_kernel<<<NROWS, blk, 0, stream>>>(tmp, x_q, nullptr, ln1_g, ln1_b, nullptr, y16);

    // ---- cross attention 1: q from y, k/v from x1 ----
    gemm_lds<64, 64, false, true ><<<g512, blk, 0, stream>>>(y16, w_in, mha_in_b, nullptr, q16, DMODEL, DMODEL);
    gemm_lds<64, 64, false, false><<<g512, blk, 0, stream>>>(x116, w_in + (size_t)DD, mha_in_b + DMODEL, nullptr, k16, DMODEL, DMODEL);
    gemm_lds<64, 64, false, false><<<g512, blk, 0, stream>>>(x116, w_in + (size_t)2 * DD, mha_in_b + 2 * DMODEL, nullptr, v16, DMODEL, DMODEL);
    attn_mfma<<<agrid, blk, 0, stream>>>(q16, k16, v16, nullptr, a16, 0);
    gemm_lds<64, 64, false, false><<<g512, blk, 0, stream>>>(a16, w_out, mha_out_b, tmp, nullptr, DMODEL, DMODEL);
    ln_kernel<<<NROWS, blk, 0, stream>>>(tmp, nullptr, y16, ln2_g, ln2_b, nullptr, ya16);

    // ---- cross attention 2: q from yattn, k/v from x2 ----
    gemm_lds<64, 64, false, true ><<<g512, blk, 0, stream>>>(ya16, w_in, mha_in_b, nullptr, q16, DMODEL, DMODEL);
    gemm_lds<64, 64, false, false><<<g512, blk, 0, stream>>>(x216, w_in + (size_t)DD, mha_in_b + DMODEL, nullptr, k16, DMODEL, DMODEL);
    gemm_lds<64, 64, false, false><<<g512, blk, 0, stream>>>(x216, w_in + (size_t)2 * DD, mha_in_b + 2 * DMODEL, nullptr, v16, DMODEL, DMODEL);
    attn_mfma<<<agrid, blk, 0, stream>>>(q16, k16, v16, nullptr, a16, 0);
    gemm_lds<64, 64, false, false><<<g512, blk, 0, stream>>>(a16, w_out, mha_out_b, tmp, nullptr, DMODEL, DMODEL);
    ln_kernel<<<NROWS, blk, 0, stream>>>(tmp, nullptr, ya16, ln2_g, ln2_b, nullptr, ya2);

    // ---- FFN ----
    gemm_lds<128, 128, true , false><<<gFF1, blk, 0, stream>>>(ya2, w_f1, ffn_b1, nullptr, h16, FFDIM, DMODEL);
    gemm_lds<64, 64, false, false><<<g512, blk, 0, stream>>>(h16, w_f2, ffn_b2, tmp, nullptr, DMODEL, FFDIM);
    ln_kernel<<<NROWS, blk, 0, stream>>>(tmp, nullptr, ya2, ln3_g, ln3_b, (float*)d_out, nullptr);
}

// Round 8
// 458.379 us; speedup vs baseline: 1.2758x; 1.0428x over previous
//
#include <hip/hip_runtime.h>
#include <hip/hip_bf16.h>

#define S_LEN 2048
#define DMODEL 512
#define NHEAD 8
#define DKH 64
#define FFDIM 2048
#define BATCH 2
#define NROWS (BATCH * S_LEN)  // 4096

using bf16 = __hip_bfloat16;
typedef __bf16 bf16x8 __attribute__((ext_vector_type(8)));
typedef float floatx4 __attribute__((ext_vector_type(4)));
typedef float floatx16 __attribute__((ext_vector_type(16)));

// fp32 -> bf16 round-to-nearest-even, branch-free (scalar path, cvt kernel)
__device__ inline unsigned short f2bf_bits(float f) {
    union { float f; unsigned u; } c; c.f = f;
    return (unsigned short)((c.u + 0x7FFFu + ((c.u >> 16) & 1u)) >> 16);
}
__device__ inline unsigned pack2bf(float a, float b) {
    return (unsigned)f2bf_bits(a) | ((unsigned)f2bf_bits(b) << 16);
}
// packed conversion (v_cvt_pk_bf16_f32 on gfx950)
__device__ inline unsigned pk2(float a, float b) {
    float2 f; f.x = a; f.y = b;
    __hip_bfloat162 h = __float22bfloat162_rn(f);
    return *(unsigned*)&h;
}

// async global->LDS, 16 bytes/lane. LDS dest is wave-uniform base + lane*16.
__device__ __forceinline__ void gload_lds16(const bf16* g, bf16* l) {
    __builtin_amdgcn_global_load_lds(
        (const __attribute__((address_space(1))) void*)(const void*)g,
        (__attribute__((address_space(3))) void*)(void*)l, 16, 0, 0);
}

// ---------------------------------------------------------------------------
// fp32 -> bf16 bulk convert, up to 12 segments in one dispatch.
// ---------------------------------------------------------------------------
struct CvtSeg { const float* s; bf16* d; int n4; };
struct CvtDesc { CvtSeg seg[12]; };

__launch_bounds__(256)
__global__ void cvt_f32_bf16(CvtDesc desc) {
    const CvtSeg sg = desc.seg[blockIdx.y];
    const int stride = gridDim.x * 256;
    for (int i = blockIdx.x * 256 + threadIdx.x; i < sg.n4; i += stride) {
        const float4 v = ((const float4*)sg.s)[i];
        uint2 o;
        o.x = pack2bf(v.x, v.y);
        o.y = pack2bf(v.z, v.w);
        ((uint2*)sg.d)[i] = o;
    }
}

// ---------------------------------------------------------------------------
// GEMM v2: C[M,N] = A[M,K] @ W[N,K]^T, BK=64 as two BK=32 panels (keeps the
// free 2-way LDS bank pattern of 64B row stride AND global_load_lds's
// wave-uniform+lane*16 LDS rule). Epilogue routes 2^shift-wide column slabs
// to up to 3 outputs with per-slab bias/scale (slab index readfirstlane'd).
// 4 waves (2x2), one barrier pair per 64-k.
// ---------------------------------------------------------------------------
struct Epi {
    bf16*  outB[3];
    float* outF[3];
    const float* bias[3];
    float scale[3];
    int shift;   // log2(slab width): 9 for 512-wide outputs, 11 for FFN1
    int relu;
};

template <int BM, int BN>
__launch_bounds__(256)
__global__ void gemm2(const bf16* __restrict__ A, const bf16* __restrict__ W,
                      Epi epi, int K)
{
    constexpr int WR = BM / 32;
    constexpr int WC = BN / 32;
    constexpr int SA = BM / 16;          // A gload segments per panel
    constexpr int SB = BN / 16;
    constexpr int NG = 2 * (SA + SB);    // gloads per iter (1KB each)

    __shared__ alignas(16) bf16 As[2][BM][32];
    __shared__ alignas(16) bf16 Bs[2][BN][32];

    const int t = threadIdx.x;
    const int w = t >> 6;
    const int lane = t & 63;
    const int r16 = lane & 15;
    const int quad = lane >> 4;
    const int wm = w >> 1, wn = w & 1;
    const int m0 = blockIdx.x * BM;
    const int n0 = blockIdx.y * BN;

    floatx4 acc[WR][WC];
#pragma unroll
    for (int i = 0; i < WR; i++)
#pragma unroll
        for (int j = 0; j < WC; j++)
#pragma unroll
            for (int e = 0; e < 4; e++) acc[i][j][e] = 0.0f;

    const int grow = lane >> 2;        // row within 16-row gload segment
    const int gcol = (lane & 3) * 8;   // k-offset within 32-panel

    for (int k0 = 0; k0 < K; k0 += 64) {
        __syncthreads();
#pragma unroll
        for (int s = 0; s < NG; s += 4) {
            int sg = s + w;
            int p = 0;
            if (sg >= SA + SB) { p = 1; sg -= SA + SB; }
            const bf16* src;
            bf16* dst;
            if (sg < SA) {
                src = A + (size_t)(m0 + sg * 16 + grow) * K + k0 + 32 * p + gcol;
                dst = &As[p][sg * 16][0] + lane * 8;
            } else {
                const int sb = sg - SA;
                src = W + (size_t)(n0 + sb * 16 + grow) * K + k0 + 32 * p + gcol;
                dst = &Bs[p][sb * 16][0] + lane * 8;
            }
            gload_lds16(src, dst);
        }
        __syncthreads();

        bf16x8 af[2][WR], bfr[2][WC];
#pragma unroll
        for (int p = 0; p < 2; p++) {
#pragma unroll
            for (int i = 0; i < WR; i++)
                af[p][i] = *(const bf16x8*)&As[p][wm * (BM / 2) + 16 * i + r16][quad * 8];
#pragma unroll
            for (int j = 0; j < WC; j++)
                bfr[p][j] = *(const bf16x8*)&Bs[p][wn * (BN / 2) + 16 * j + r16][quad * 8];
        }
#pragma unroll
        for (int p = 0; p < 2; p++)
#pragma unroll
            for (int i = 0; i < WR; i++)
#pragma unroll
                for (int j = 0; j < WC; j++)
                    acc[i][j] = __builtin_amdgcn_mfma_f32_16x16x32_bf16(af[p][i], bfr[p][j], acc[i][j], 0, 0, 0);
    }

    const int mask = (1 << epi.shift) - 1;
#pragma unroll
    for (int j = 0; j < WC; j++) {
        const int colb = n0 + wn * (BN / 2) + 16 * j;
        const int sel = __builtin_amdgcn_readfirstlane(colb >> epi.shift);
        const int lcol = (colb & mask) + r16;
        const int ldw = mask + 1;
        const float bv = epi.bias[sel] ? epi.bias[sel][lcol] : 0.0f;
        const float sc = epi.scale[sel];
        bf16* ob = epi.outB[sel];
        float* of = epi.outF[sel];
#pragma unroll
        for (int i = 0; i < WR; i++) {
            const int rowb = m0 + wm * (BM / 2) + 16 * i + 4 * quad;
#pragma unroll
            for (int e = 0; e < 4; e++) {
                float v = (acc[i][j][e] + bv) * sc;
                if (epi.relu) v = fmaxf(v, 0.0f);
                const size_t idx = (size_t)(rowb + e) * ldw + lcol;
                if (of) of[idx] = v;
                if (ob) ob[idx] = __float2bfloat16(v);
            }
        }
    }
}

// ---------------------------------------------------------------------------
// Flash attention, 32x32x16 MFMA, key-split across wave-pairs (round-7
// structure) + packed bf16 cvt + skip O-rescale when the running max is
// unchanged wave-wide.
// ---------------------------------------------------------------------------
#define PST 72  // LDS row stride (bf16): 64 + 8, keeps b128 alignment

__launch_bounds__(256)
__global__ void attn_mfma(const bf16* __restrict__ Qh, const bf16* __restrict__ Kh,
                          const bf16* __restrict__ Vh,
                          float* __restrict__ outF, bf16* __restrict__ outB,
                          int causal)
{
    __shared__ alignas(16) bf16 Vt[2][64][PST];    // per-pair [d][key]
    __shared__ alignas(16) bf16 Ps[4][32][PST];    // per-wave [q][key]
    __shared__ float Msh[2][64][34];               // merge scratch

    const int t = threadIdx.x;        // 0..255
    const int w = t >> 6;
    const int lane = t & 63;
    const int c32 = lane & 31;
    const int hi = lane >> 5;
    const int pair = t >> 7;
    const int qg = w & 1;
    const int pl = t & 127;
    const int bh = blockIdx.y;
    const int b = bh >> 3, h = bh & 7;
    const int q0 = blockIdx.x * 64;
    const size_t rowbase = (size_t)b * S_LEN;
    const int hoff = h * DKH;

    bf16x8 qf[4];
    {
        const bf16* qp = Qh + (rowbase + q0 + 32 * qg + c32) * DMODEL + hoff + 8 * hi;
#pragma unroll
        for (int tt = 0; tt < 4; tt++) qf[tt] = *(const bf16x8*)(qp + 16 * tt);
    }

    floatx16 o0, o1;
#pragma unroll
    for (int e = 0; e < 16; e++) { o0[e] = 0.0f; o1[e] = 0.0f; }
    float m = -3e38f, l = 0.0f;

    const int rq = pl & 15;
    const int c8 = ((pl >> 4) & 7) * 8;

    const int nchunk = causal ? (q0 / 64 + 1) : (S_LEN / 64);
    const int nIter = (nchunk + 1) >> 1;

    for (int it = 0; it < nIter; it++) {
        const int ch = 2 * it + pair;
        const bool active = ch < nchunk;
        const int kb = ch * 64;
        __syncthreads();
        if (active) {      // stage V transposed (packed b64 writes)
            union { uint4 u; unsigned short s[8]; } r0, r1, r2, r3;
            const bf16* vb = Vh + (rowbase + kb + 4 * rq) * DMODEL + hoff + c8;
            r0.u = *(const uint4*)(vb);
            r1.u = *(const uint4*)(vb + DMODEL);
            r2.u = *(const uint4*)(vb + 2 * DMODEL);
            r3.u = *(const uint4*)(vb + 3 * DMODEL);
#pragma unroll
            for (int j = 0; j < 8; j++) {
                ushort4 pk = { r0.s[j], r1.s[j], r2.s[j], r3.s[j] };
                *(ushort4*)&Vt[pair][c8 + j][4 * rq] = pk;
            }
        }

        if (active) {
            floatx16 s0, s1;
#pragma unroll
            for (int e = 0; e < 16; e++) { s0[e] = 0.0f; s1[e] = 0.0f; }
            const bf16* kp = Kh + (rowbase + kb + c32) * DMODEL + hoff + 8 * hi;
#pragma unroll
            for (int tt = 0; tt < 4; tt++) {
                const bf16x8 k0 = *(const bf16x8*)(kp + 16 * tt);
                const bf16x8 k1 = *(const bf16x8*)(kp + (size_t)32 * DMODEL + 16 * tt);
                s0 = __builtin_amdgcn_mfma_f32_32x32x16_bf16(k0, qf[tt], s0, 0, 0, 0);
                s1 = __builtin_amdgcn_mfma_f32_32x32x16_bf16(k1, qf[tt], s1, 0, 0, 0);
            }

            if (causal && kb == q0) {
                const int qq = 32 * qg + c32;
#pragma unroll
                for (int r = 0; r < 16; r++) {
                    const int kl = (r & 3) + 8 * (r >> 2) + 4 * hi;
                    if (kl > qq) s0[r] = -3e38f;
                    if (kl + 32 > qq) s1[r] = -3e38f;
                }
            }

            float mc = -3e38f;
#pragma unroll
            for (int r = 0; r < 16; r++) mc = fmaxf(mc, fmaxf(s0[r], s1[r]));
            mc = fmaxf(mc, __shfl_xor(mc, 32, 64));
            const float mold = m;
            const float mn = fmaxf(m, mc);
            const float alpha = __expf(mold - mn);
            m = mn;

            float lc = 0.0f;
#pragma unroll
            for (int g = 0; g < 4; g++) {
                float p0 = __expf(s0[4 * g + 0] - mn), p1 = __expf(s0[4 * g + 1] - mn);
                float p2 = __expf(s0[4 * g + 2] - mn), p3 = __expf(s0[4 * g + 3] - mn);
                lc += (p0 + p1) + (p2 + p3);
                uint2 pw; pw.x = pk2(p0, p1); pw.y = pk2(p2, p3);
                *(uint2*)&Ps[w][c32][8 * g + 4 * hi] = pw;
                p0 = __expf(s1[4 * g + 0] - mn); p1 = __expf(s1[4 * g + 1] - mn);
                p2 = __expf(s1[4 * g + 2] - mn); p3 = __expf(s1[4 * g + 3] - mn);
                lc += (p0 + p1) + (p2 + p3);
                uint2 pw1; pw1.x = pk2(p0, p1); pw1.y = pk2(p2, p3);
                *(uint2*)&Ps[w][c32][32 + 8 * g + 4 * hi] = pw1;
            }
            lc += __shfl_xor(lc, 32, 64);
            l = l * alpha + lc;

            // O-rescale only if some lane's running max moved
            if (!__all(mn == mold)) {
#pragma unroll
                for (int r = 0; r < 16; r++) {
                    const float a = __shfl(alpha, (r & 3) + 8 * (r >> 2) + 4 * hi, 64);
                    o0[r] *= a; o1[r] *= a;
                }
            }
        }

        __syncthreads();

        if (active) {
#pragma unroll
            for (int tt = 0; tt < 4; tt++) {
                const bf16x8 pf = *(const bf16x8*)&Ps[w][c32][16 * tt + 8 * hi];
                const bf16x8 v0 = *(const bf16x8*)&Vt[pair][c32][16 * tt + 8 * hi];
                const bf16x8 v1 = *(const bf16x8*)&Vt[pair][32 + c32][16 * tt + 8 * hi];
                o0 = __builtin_amdgcn_mfma_f32_32x32x16_bf16(pf, v0, o0, 0, 0, 0);
                o1 = __builtin_amdgcn_mfma_f32_32x32x16_bf16(pf, v1, o1, 0, 0, 0);
            }
        }
    }

    // ---- split-KV merge: pair1 -> LDS, pair0 combines & writes ----
    __syncthreads();
    if (pair == 1) {
        float* dst = &Msh[qg][lane][0];
        dst[0] = m; dst[1] = l;
#pragma unroll
        for (int r = 0; r < 16; r++) { dst[2 + r] = o0[r]; dst[18 + r] = o1[r]; }
    }
    __syncthreads();
    if (pair == 0) {
        const float* src = &Msh[qg][lane][0];
        const float m_b = src[0], l_b = src[1];
        const float mt = fmaxf(m, m_b);
        const float sA = __expf(m - mt);
        const float sB = __expf(m_b - mt);
        const float lt = l * sA + l_b * sB;
#pragma unroll
        for (int r = 0; r < 16; r++) {
            const int ql = (r & 3) + 8 * (r >> 2) + 4 * hi;
            const float sAr = __shfl(sA, ql, 64);
            const float sBr = __shfl(sB, ql, 64);
            const float li = 1.0f / __shfl(lt, ql, 64);
            const float v0 = (o0[r] * sAr + src[2 + r] * sBr) * li;
            const float v1 = (o1[r] * sAr + src[18 + r] * sBr) * li;
            const size_t idx = (rowbase + q0 + 32 * qg + ql) * DMODEL + hoff + c32;
            if (outF) { outF[idx] = v0; outF[idx + 32] = v1; }
            if (outB) { outB[idx] = __float2bfloat16(v0); outB[idx + 32] = __float2bfloat16(v1); }
        }
    }
}

// ---------------------------------------------------------------------------
// Fused residual + LayerNorm over D=512. One WG (256 thr) per row.
// ---------------------------------------------------------------------------
__launch_bounds__(256)
__global__ void ln_kernel(const float* __restrict__ xmain,
                          const float* __restrict__ resF, const bf16* __restrict__ resB,
                          const float* __restrict__ g, const float* __restrict__ bb,
                          float* __restrict__ outF, bf16* __restrict__ outB)
{
    const int row = blockIdx.x;
    const int t = threadIdx.x;
    const size_t base = (size_t)row * DMODEL;

    float x0 = xmain[base + t];
    float x1 = xmain[base + t + 256];
    if (resF) { x0 += resF[base + t]; x1 += resF[base + t + 256]; }
    if (resB) { x0 += __bfloat162float(resB[base + t]); x1 += __bfloat162float(resB[base + t + 256]); }

    __shared__ float sred[4];
    float s = x0 + x1;
#pragma unroll
    for (int off = 32; off > 0; off >>= 1) s += __shfl_down(s, off);
    if ((t & 63) == 0) sred[t >> 6] = s;
    __syncthreads();
    const float mu = (sred[0] + sred[1] + sred[2] + sred[3]) * (1.0f / DMODEL);

    const float d0 = x0 - mu, d1 = x1 - mu;
    float sv = d0 * d0 + d1 * d1;
#pragma unroll
    for (int off = 32; off > 0; off >>= 1) sv += __shfl_down(sv, off);
    __syncthreads();
    if ((t & 63) == 0) sred[t >> 6] = sv;
    __syncthreads();
    const float var = (sred[0] + sred[1] + sred[2] + sred[3]) * (1.0f / DMODEL);
    const float rstd = rsqrtf(var + 1e-5f);

    const float y0 = d0 * rstd * g[t] + bb[t];
    const float y1 = d1 * rstd * g[t + 256] + bb[t + 256];
    if (outF) { outF[base + t] = y0; outF[base + t + 256] = y1; }
    if (outB) { outB[base + t] = __float2bfloat16(y0); outB[base + t + 256] = __float2bfloat16(y1); }
}

// ---------------------------------------------------------------------------
// Workspace layout (55.5 MB) — see round 5 comment. w_sa_q/k/v and the w_in
// sections are contiguous, enabling the fused N=1536 / N=1024 GEMMs.
// ---------------------------------------------------------------------------
extern "C" void kernel_launch(void* const* d_in, const int* in_sizes, int n_in,
                              void* d_out, int out_size, void* d_ws, size_t ws_size,
                              hipStream_t stream)
{
    const float* x_q       = (const float*)d_in[0];
    const float* x1        = (const float*)d_in[1];
    const float* x2        = (const float*)d_in[2];
    const float* sa_wq     = (const float*)d_in[3];
    const float* sa_bq     = (const float*)d_in[4];
    const float* sa_wk     = (const float*)d_in[5];
    const float* sa_bk     = (const float*)d_in[6];
    const float* sa_wv     = (const float*)d_in[7];
    const float* sa_bv     = (const float*)d_in[8];
    const float* ln1_g     = (const float*)d_in[9];
    const float* ln1_b     = (const float*)d_in[10];
    const float* mha_in_w  = (const float*)d_in[11];
    const float* mha_in_b  = (const float*)d_in[12];
    const float* mha_out_w = (const float*)d_in[13];
    const float* mha_out_b = (const float*)d_in[14];
    const float* ln2_g     = (const float*)d_in[15];
    const float* ln2_b     = (const float*)d_in[16];
    const float* ffn_w1    = (const float*)d_in[17];
    const float* ffn_b1    = (const float*)d_in[18];
    const float* ffn_w2    = (const float*)d_in[19];
    const float* ffn_b2    = (const float*)d_in[20];
    const float* ln3_g     = (const float*)d_in[21];
    const float* ln3_b     = (const float*)d_in[22];

    char* ws = (char*)d_ws;
    const size_t MB = 1024 * 1024;
    const size_t KB = 1024;
    bf16*  q16  = (bf16*)(ws + 0 * MB);
    bf16*  k16  = (bf16*)(ws + 4 * MB);
    bf16*  v16  = (bf16*)(ws + 8 * MB);
    bf16*  a16  = (bf16*)(ws + 12 * MB);
    float* tmp  = (float*)(ws + 16 * MB);
    bf16*  y16  = (bf16*)(ws + 24 * MB);
    bf16*  ya16 = (bf16*)(ws + 28 * MB);
    bf16*  ya2  = (bf16*)(ws + 32 * MB);
    bf16*  xq16 = (bf16*)(ws + 36 * MB);
    bf16*  x116 = (bf16*)(ws + 40 * MB);
    bf16*  x216 = (bf16*)(ws + 44 * MB);
    bf16*  w_sa_qkv = (bf16*)(ws + 48 * MB);            // 1.5 MB (3D x D contig)
    bf16*  w_in   = (bf16*)(ws + 49 * MB + 512 * KB);   // 1.5 MB
    bf16*  w_out  = (bf16*)(ws + 51 * MB);              // 0.5 MB
    bf16*  w_f1   = (bf16*)(ws + 51 * MB + 512 * KB);   // 2 MB
    bf16*  w_f2   = (bf16*)(ws + 53 * MB + 512 * KB);   // 2 MB
    bf16*  h16    = (bf16*)(ws + 0 * MB);               // aliases q..a (dead by FFN)

    const int DD = DMODEL * DMODEL;
    CvtDesc cd;
    cd.seg[0]  = { x_q,       xq16,        (NROWS * DMODEL) / 4 };
    cd.seg[1]  = { x1,        x116,        (NROWS * DMODEL) / 4 };
    cd.seg[2]  = { x2,        x216,        (NROWS * DMODEL) / 4 };
    cd.seg[3]  = { sa_wq,     w_sa_qkv,           DD / 4 };
    cd.seg[4]  = { sa_wk,     w_sa_qkv + DD,      DD / 4 };
    cd.seg[5]  = { sa_wv,     w_sa_qkv + 2 * DD,  DD / 4 };
    cd.seg[6]  = { mha_in_w,  w_in,   3 * DD / 4 };
    cd.seg[7]  = { mha_out_w, w_out,  DD / 4 };
    cd.seg[8]  = { ffn_w1,    w_f1,   (FFDIM * DMODEL) / 4 };
    cd.seg[9]  = { ffn_w2,    w_f2,   (FFDIM * DMODEL) / 4 };
    cd.seg[10] = { x_q,       xq16,   0 };
    cd.seg[11] = { x_q,       xq16,   0 };
    cvt_f32_bf16<<<dim3(64, 10), 256, 0, stream>>>(cd);

    const dim3 blk(256);
    const dim3 agrid(S_LEN / 64, BATCH * NHEAD);   // (32,16)

    Epi eQKV = {};   // self Q/K/V fused, N=1536 -> q16|k16|v16
    eQKV.outB[0] = q16; eQKV.outB[1] = k16; eQKV.outB[2] = v16;
    eQKV.bias[0] = sa_bq; eQKV.bias[1] = sa_bk; eQKV.bias[2] = sa_bv;
    eQKV.scale[0] = 0.125f; eQKV.scale[1] = 1.0f; eQKV.scale[2] = 1.0f;
    eQKV.shift = 9;

    Epi eQ = {};     // cross Q, N=512 -> q16 (pre-scaled)
    eQ.outB[0] = q16; eQ.bias[0] = mha_in_b; eQ.scale[0] = 0.125f; eQ.shift = 9;

    Epi eKV = {};    // cross K/V fused, N=1024 -> k16|v16
    eKV.outB[0] = k16; eKV.outB[1] = v16;
    eKV.bias[0] = mha_in_b + DMODEL; eKV.bias[1] = mha_in_b + 2 * DMODEL;
    eKV.scale[0] = 1.0f; eKV.scale[1] = 1.0f; eKV.shift = 9;

    Epi eOut = {};   // out-proj, N=512 -> tmp (fp32)
    eOut.outF[0] = tmp; eOut.bias[0] = mha_out_b; eOut.scale[0] = 1.0f; eOut.shift = 9;

    Epi eF1 = {};    // FFN1, N=2048 -> h16, relu
    eF1.outB[0] = h16; eF1.bias[0] = ffn_b1; eF1.scale[0] = 1.0f;
    eF1.shift = 11; eF1.relu = 1;

    Epi eF2 = {};    // FFN2, N=512 -> tmp (fp32)
    eF2.outF[0] = tmp; eF2.bias[0] = ffn_b2; eF2.scale[0] = 1.0f; eF2.shift = 9;

    // ---- self attention (causal, no out-proj) ----
    gemm2<64, 64><<<dim3(64, 24), blk, 0, stream>>>(xq16, w_sa_qkv, eQKV, DMODEL);
    attn_mfma<<<agrid, blk, 0, stream>>>(q16, k16, v16, tmp, nullptr, 1);
    ln_kernel<<<NROWS, blk, 0, stream>>>(tmp, x_q, nullptr, ln1_g, ln1_b, nullptr, y16);

    // ---- cross attention 1: q from y, k/v from x1 ----
    gemm2<64, 64><<<dim3(64, 8), blk, 0, stream>>>(y16, w_in, eQ, DMODEL);
    gemm2<64, 64><<<dim3(64, 16), blk, 0, stream>>>(x116, w_in + (size_t)DD, eKV, DMODEL);
    attn_mfma<<<agrid, blk, 0, stream>>>(q16, k16, v16, nullptr, a16, 0);
    gemm2<64, 64><<<dim3(64, 8), blk, 0, stream>>>(a16, w_out, eOut, DMODEL);
    ln_kernel<<<NROWS, blk, 0, stream>>>(tmp, nullptr, y16, ln2_g, ln2_b, nullptr, ya16);

    // ---- cross attention 2: q from yattn, k/v from x2 ----
    gemm2<64, 64><<<dim3(64, 8), blk, 0, stream>>>(ya16, w_in, eQ, DMODEL);
    gemm2<64, 64><<<dim3(64, 16), blk, 0, stream>>>(x216, w_in + (size_t)DD, eKV, DMODEL);
    attn_mfma<<<agrid, blk, 0, stream>>>(q16, k16, v16, nullptr, a16, 0);
    gemm2<64, 64><<<dim3(64, 8), blk, 0, stream>>>(a16, w_out, eOut, DMODEL);
    ln_kernel<<<NROWS, blk, 0, stream>>>(tmp, nullptr, ya16, ln2_g, ln2_b, nullptr, ya2);

    // ---- FFN ----
    gemm2<128, 128><<<dim3(32, 16), blk, 0, stream>>>(ya2, w_f1, eF1, DMODEL);
    gemm2<64, 64><<<dim3(64, 8), blk, 0, stream>>>(h16, w_f2, eF2, FFDIM);
    ln_kernel<<<NROWS, blk, 0, stream>>>(tmp, nullptr, ya2, ln3_g, ln3_b, (float*)d_out, nullptr);
}

// Round 9
// 441.324 us; speedup vs baseline: 1.3251x; 1.0386x over previous
//
#include <hip/hip_runtime.h>
#include <hip/hip_bf16.h>

#define S_LEN 2048
#define DMODEL 512
#define NHEAD 8
#define DKH 64
#define FFDIM 2048
#define BATCH 2
#define NROWS (BATCH * S_LEN)  // 4096

using bf16 = __hip_bfloat16;
typedef __bf16 bf16x8 __attribute__((ext_vector_type(8)));
typedef float floatx4 __attribute__((ext_vector_type(4)));
typedef float floatx16 __attribute__((ext_vector_type(16)));

// fp32 -> bf16 round-to-nearest-even, branch-free (scalar path, cvt kernel)
__device__ inline unsigned short f2bf_bits(float f) {
    union { float f; unsigned u; } c; c.f = f;
    return (unsigned short)((c.u + 0x7FFFu + ((c.u >> 16) & 1u)) >> 16);
}
__device__ inline unsigned pack2bf(float a, float b) {
    return (unsigned)f2bf_bits(a) | ((unsigned)f2bf_bits(b) << 16);
}
// packed conversion (v_cvt_pk_bf16_f32 on gfx950)
__device__ inline unsigned pk2(float a, float b) {
    float2 f; f.x = a; f.y = b;
    __hip_bfloat162 h = __float22bfloat162_rn(f);
    return *(unsigned*)&h;
}

// async global->LDS, 16 bytes/lane. LDS dest is wave-uniform base + lane*16.
__device__ __forceinline__ void gload_lds16(const bf16* g, bf16* l) {
    __builtin_amdgcn_global_load_lds(
        (const __attribute__((address_space(1))) void*)(const void*)g,
        (__attribute__((address_space(3))) void*)(void*)l, 16, 0, 0);
}

// ---------------------------------------------------------------------------
// fp32 -> bf16 bulk convert, up to 12 segments in one dispatch.
// ---------------------------------------------------------------------------
struct CvtSeg { const float* s; bf16* d; int n4; };
struct CvtDesc { CvtSeg seg[12]; };

__launch_bounds__(256)
__global__ void cvt_f32_bf16(CvtDesc desc) {
    const CvtSeg sg = desc.seg[blockIdx.y];
    const int stride = gridDim.x * 256;
    for (int i = blockIdx.x * 256 + threadIdx.x; i < sg.n4; i += stride) {
        const float4 v = ((const float4*)sg.s)[i];
        uint2 o;
        o.x = pack2bf(v.x, v.y);
        o.y = pack2bf(v.z, v.w);
        ((uint2*)sg.d)[i] = o;
    }
}

// ---------------------------------------------------------------------------
// GEMM v2: C[M,N] = A[M,K] @ W[N,K]^T, BK=64 as two BK=32 panels. Epilogue
// routes 2^shift-wide column slabs to up to 3 outputs with per-slab bias/
// scale; A2 (if set) replaces A for slabs >= a2slab (fused cross Q|K|V with
// different activation sources). 4 waves (2x2), one barrier pair per 64-k.
// ---------------------------------------------------------------------------
struct Epi {
    bf16*  outB[3];
    float* outF[3];
    const float* bias[3];
    float scale[3];
    const bf16* A2;   // alternate A source for slabs >= a2slab (or null)
    int a2slab;
    int shift;        // log2(slab width): 9 for 512-wide outputs, 11 for FFN1
    int relu;
};

template <int BM, int BN>
__launch_bounds__(256)
__global__ void gemm2(const bf16* __restrict__ A, const bf16* __restrict__ W,
                      Epi epi, int K)
{
    constexpr int WR = BM / 32;
    constexpr int WC = BN / 32;
    constexpr int SA = BM / 16;          // A gload segments per panel
    constexpr int SB = BN / 16;
    constexpr int NG = 2 * (SA + SB);    // gloads per iter (1KB each)

    __shared__ alignas(16) bf16 As[2][BM][32];
    __shared__ alignas(16) bf16 Bs[2][BN][32];

    const int t = threadIdx.x;
    const int w = t >> 6;
    const int lane = t & 63;
    const int r16 = lane & 15;
    const int quad = lane >> 4;
    const int wm = w >> 1, wn = w & 1;
    const int m0 = blockIdx.x * BM;
    const int n0 = blockIdx.y * BN;

    const bf16* Ause = (epi.A2 && ((n0 >> epi.shift) >= epi.a2slab)) ? epi.A2 : A;

    floatx4 acc[WR][WC];
#pragma unroll
    for (int i = 0; i < WR; i++)
#pragma unroll
        for (int j = 0; j < WC; j++)
#pragma unroll
            for (int e = 0; e < 4; e++) acc[i][j][e] = 0.0f;

    const int grow = lane >> 2;        // row within 16-row gload segment
    const int gcol = (lane & 3) * 8;   // k-offset within 32-panel

    for (int k0 = 0; k0 < K; k0 += 64) {
        __syncthreads();
#pragma unroll
        for (int s = 0; s < NG; s += 4) {
            int sg = s + w;
            int p = 0;
            if (sg >= SA + SB) { p = 1; sg -= SA + SB; }
            const bf16* src;
            bf16* dst;
            if (sg < SA) {
                src = Ause + (size_t)(m0 + sg * 16 + grow) * K + k0 + 32 * p + gcol;
                dst = &As[p][sg * 16][0] + lane * 8;
            } else {
                const int sb = sg - SA;
                src = W + (size_t)(n0 + sb * 16 + grow) * K + k0 + 32 * p + gcol;
                dst = &Bs[p][sb * 16][0] + lane * 8;
            }
            gload_lds16(src, dst);
        }
        __syncthreads();

        bf16x8 af[2][WR], bfr[2][WC];
#pragma unroll
        for (int p = 0; p < 2; p++) {
#pragma unroll
            for (int i = 0; i < WR; i++)
                af[p][i] = *(const bf16x8*)&As[p][wm * (BM / 2) + 16 * i + r16][quad * 8];
#pragma unroll
            for (int j = 0; j < WC; j++)
                bfr[p][j] = *(const bf16x8*)&Bs[p][wn * (BN / 2) + 16 * j + r16][quad * 8];
        }
#pragma unroll
        for (int p = 0; p < 2; p++)
#pragma unroll
            for (int i = 0; i < WR; i++)
#pragma unroll
                for (int j = 0; j < WC; j++)
                    acc[i][j] = __builtin_amdgcn_mfma_f32_16x16x32_bf16(af[p][i], bfr[p][j], acc[i][j], 0, 0, 0);
    }

    const int mask = (1 << epi.shift) - 1;
#pragma unroll
    for (int j = 0; j < WC; j++) {
        const int colb = n0 + wn * (BN / 2) + 16 * j;
        const int sel = __builtin_amdgcn_readfirstlane(colb >> epi.shift);
        const int lcol = (colb & mask) + r16;
        const int ldw = mask + 1;
        const float bv = epi.bias[sel] ? epi.bias[sel][lcol] : 0.0f;
        const float sc = epi.scale[sel];
        bf16* ob = epi.outB[sel];
        float* of = epi.outF[sel];
#pragma unroll
        for (int i = 0; i < WR; i++) {
            const int rowb = m0 + wm * (BM / 2) + 16 * i + 4 * quad;
#pragma unroll
            for (int e = 0; e < 4; e++) {
                float v = (acc[i][j][e] + bv) * sc;
                if (epi.relu) v = fmaxf(v, 0.0f);
                const size_t idx = (size_t)(rowb + e) * ldw + lcol;
                if (of) of[idx] = v;
                if (ob) ob[idx] = __float2bfloat16(v);
            }
        }
    }
}

// ---------------------------------------------------------------------------
// Flash attention, 32x32x16 MFMA, key-split across wave-pairs.
// Round-9 changes: (a) merge scratch Msh OVERLAYS Vt (dead after the K-loop's
// final barrier) -> LDS 54->36.9 KB -> 4 blocks/CU; (b) K-fragment software
// prefetch: chunk ch+2's K loads issue right after the S-MFMAs, overlapping
// softmax VALU + PV MFMA with the L2 latency.
// ---------------------------------------------------------------------------
#define PST 72  // LDS row stride (bf16): 64 + 8, keeps b128 alignment

__launch_bounds__(256)
__global__ void attn_mfma(const bf16* __restrict__ Qh, const bf16* __restrict__ Kh,
                          const bf16* __restrict__ Vh,
                          float* __restrict__ outF, bf16* __restrict__ outB,
                          int causal)
{
    // [0,18432): Vt[2][64][PST]  (bf16)   -- overlaid by Msh[2][64][34] (fp32,
    // [18432,36864): Ps[4][32][PST]          17408B) after the K-loop
    __shared__ alignas(16) char smem[36864];
    typedef bf16 (*VtT)[64][PST];
    typedef bf16 (*PsT)[32][PST];
    VtT Vt = (VtT)smem;
    PsT Ps = (PsT)(smem + 18432);
    typedef float (*MshT)[64][34];
    MshT Msh = (MshT)smem;

    const int t = threadIdx.x;        // 0..255
    const int w = t >> 6;
    const int lane = t & 63;
    const int c32 = lane & 31;
    const int hi = lane >> 5;
    const int pair = t >> 7;
    const int qg = w & 1;
    const int pl = t & 127;
    const int bh = blockIdx.y;
    const int b = bh >> 3, h = bh & 7;
    const int q0 = blockIdx.x * 64;
    const size_t rowbase = (size_t)b * S_LEN;
    const int hoff = h * DKH;

    bf16x8 qf[4];
    {
        const bf16* qp = Qh + (rowbase + q0 + 32 * qg + c32) * DMODEL + hoff + 8 * hi;
#pragma unroll
        for (int tt = 0; tt < 4; tt++) qf[tt] = *(const bf16x8*)(qp + 16 * tt);
    }

    floatx16 o0, o1;
#pragma unroll
    for (int e = 0; e < 16; e++) { o0[e] = 0.0f; o1[e] = 0.0f; }
    float m = -3e38f, l = 0.0f;

    const int rq = pl & 15;
    const int c8 = ((pl >> 4) & 7) * 8;

    const int nchunk = causal ? (q0 / 64 + 1) : (S_LEN / 64);
    const int nIter = (nchunk + 1) >> 1;

    // K-fragment prefetch registers (this wave's chunks: pair, pair+2, ...)
    bf16x8 kf0[4], kf1[4];
    if (pair < nchunk) {
        const bf16* kp = Kh + (rowbase + pair * 64 + c32) * DMODEL + hoff + 8 * hi;
#pragma unroll
        for (int tt = 0; tt < 4; tt++) {
            kf0[tt] = *(const bf16x8*)(kp + 16 * tt);
            kf1[tt] = *(const bf16x8*)(kp + (size_t)32 * DMODEL + 16 * tt);
        }
    }

    for (int it = 0; it < nIter; it++) {
        const int ch = 2 * it + pair;
        const bool active = ch < nchunk;
        const int kb = ch * 64;
        __syncthreads();
        if (active) {      // stage V transposed (packed b64 writes)
            union { uint4 u; unsigned short s[8]; } r0, r1, r2, r3;
            const bf16* vb = Vh + (rowbase + kb + 4 * rq) * DMODEL + hoff + c8;
            r0.u = *(const uint4*)(vb);
            r1.u = *(const uint4*)(vb + DMODEL);
            r2.u = *(const uint4*)(vb + 2 * DMODEL);
            r3.u = *(const uint4*)(vb + 3 * DMODEL);
#pragma unroll
            for (int j = 0; j < 8; j++) {
                ushort4 pk = { r0.s[j], r1.s[j], r2.s[j], r3.s[j] };
                *(ushort4*)&Vt[pair][c8 + j][4 * rq] = pk;
            }
        }

        if (active) {
            floatx16 s0, s1;
#pragma unroll
            for (int e = 0; e < 16; e++) { s0[e] = 0.0f; s1[e] = 0.0f; }
#pragma unroll
            for (int tt = 0; tt < 4; tt++) {
                s0 = __builtin_amdgcn_mfma_f32_32x32x16_bf16(kf0[tt], qf[tt], s0, 0, 0, 0);
                s1 = __builtin_amdgcn_mfma_f32_32x32x16_bf16(kf1[tt], qf[tt], s1, 0, 0, 0);
            }

            // prefetch next chunk's K frags (overlaps softmax + PV below)
            const int chn = ch + 2;
            if (chn < nchunk) {
                const bf16* kp = Kh + (rowbase + chn * 64 + c32) * DMODEL + hoff + 8 * hi;
#pragma unroll
                for (int tt = 0; tt < 4; tt++) {
                    kf0[tt] = *(const bf16x8*)(kp + 16 * tt);
                    kf1[tt] = *(const bf16x8*)(kp + (size_t)32 * DMODEL + 16 * tt);
                }
            }

            if (causal && kb == q0) {
                const int qq = 32 * qg + c32;
#pragma unroll
                for (int r = 0; r < 16; r++) {
                    const int kl = (r & 3) + 8 * (r >> 2) + 4 * hi;
                    if (kl > qq) s0[r] = -3e38f;
                    if (kl + 32 > qq) s1[r] = -3e38f;
                }
            }

            float mc = -3e38f;
#pragma unroll
            for (int r = 0; r < 16; r++) mc = fmaxf(mc, fmaxf(s0[r], s1[r]));
            mc = fmaxf(mc, __shfl_xor(mc, 32, 64));
            const float mold = m;
            const float mn = fmaxf(m, mc);
            const float alpha = __expf(mold - mn);
            m = mn;

            float lc = 0.0f;
#pragma unroll
            for (int g = 0; g < 4; g++) {
                float p0 = __expf(s0[4 * g + 0] - mn), p1 = __expf(s0[4 * g + 1] - mn);
                float p2 = __expf(s0[4 * g + 2] - mn), p3 = __expf(s0[4 * g + 3] - mn);
                lc += (p0 + p1) + (p2 + p3);
                uint2 pw; pw.x = pk2(p0, p1); pw.y = pk2(p2, p3);
                *(uint2*)&Ps[w][c32][8 * g + 4 * hi] = pw;
                p0 = __expf(s1[4 * g + 0] - mn); p1 = __expf(s1[4 * g + 1] - mn);
                p2 = __expf(s1[4 * g + 2] - mn); p3 = __expf(s1[4 * g + 3] - mn);
                lc += (p0 + p1) + (p2 + p3);
                uint2 pw1; pw1.x = pk2(p0, p1); pw1.y = pk2(p2, p3);
                *(uint2*)&Ps[w][c32][32 + 8 * g + 4 * hi] = pw1;
            }
            lc += __shfl_xor(lc, 32, 64);
            l = l * alpha + lc;

            if (!__all(mn == mold)) {
#pragma unroll
                for (int r = 0; r < 16; r++) {
                    const float a = __shfl(alpha, (r & 3) + 8 * (r >> 2) + 4 * hi, 64);
                    o0[r] *= a; o1[r] *= a;
                }
            }
        }

        __syncthreads();

        if (active) {
#pragma unroll
            for (int tt = 0; tt < 4; tt++) {
                const bf16x8 pf = *(const bf16x8*)&Ps[w][c32][16 * tt + 8 * hi];
                const bf16x8 v0 = *(const bf16x8*)&Vt[pair][c32][16 * tt + 8 * hi];
                const bf16x8 v1 = *(const bf16x8*)&Vt[pair][32 + c32][16 * tt + 8 * hi];
                o0 = __builtin_amdgcn_mfma_f32_32x32x16_bf16(pf, v0, o0, 0, 0, 0);
                o1 = __builtin_amdgcn_mfma_f32_32x32x16_bf16(pf, v1, o1, 0, 0, 0);
            }
        }
    }

    // ---- split-KV merge: pair1 -> LDS (overlaying Vt), pair0 combines ----
    __syncthreads();   // all PV reads of Vt done -> safe to overlay
    if (pair == 1) {
        float* dst = &Msh[qg][lane][0];
        dst[0] = m; dst[1] = l;
#pragma unroll
        for (int r = 0; r < 16; r++) { dst[2 + r] = o0[r]; dst[18 + r] = o1[r]; }
    }
    __syncthreads();
    if (pair == 0) {
        const float* src = &Msh[qg][lane][0];
        const float m_b = src[0], l_b = src[1];
        const float mt = fmaxf(m, m_b);
        const float sA = __expf(m - mt);
        const float sB = __expf(m_b - mt);
        const float lt = l * sA + l_b * sB;
#pragma unroll
        for (int r = 0; r < 16; r++) {
            const int ql = (r & 3) + 8 * (r >> 2) + 4 * hi;
            const float sAr = __shfl(sA, ql, 64);
            const float sBr = __shfl(sB, ql, 64);
            const float li = 1.0f / __shfl(lt, ql, 64);
            const float v0 = (o0[r] * sAr + src[2 + r] * sBr) * li;
            const float v1 = (o1[r] * sAr + src[18 + r] * sBr) * li;
            const size_t idx = (rowbase + q0 + 32 * qg + ql) * DMODEL + hoff + c32;
            if (outF) { outF[idx] = v0; outF[idx + 32] = v1; }
            if (outB) { outB[idx] = __float2bfloat16(v0); outB[idx + 32] = __float2bfloat16(v1); }
        }
    }
}

// ---------------------------------------------------------------------------
// Fused residual + LayerNorm over D=512. One WG (256 thr) per row.
// ---------------------------------------------------------------------------
__launch_bounds__(256)
__global__ void ln_kernel(const float* __restrict__ xmain,
                          const float* __restrict__ resF, const bf16* __restrict__ resB,
                          const float* __restrict__ g, const float* __restrict__ bb,
                          float* __restrict__ outF, bf16* __restrict__ outB)
{
    const int row = blockIdx.x;
    const int t = threadIdx.x;
    const size_t base = (size_t)row * DMODEL;

    float x0 = xmain[base + t];
    float x1 = xmain[base + t + 256];
    if (resF) { x0 += resF[base + t]; x1 += resF[base + t + 256]; }
    if (resB) { x0 += __bfloat162float(resB[base + t]); x1 += __bfloat162float(resB[base + t + 256]); }

    __shared__ float sred[4];
    float s = x0 + x1;
#pragma unroll
    for (int off = 32; off > 0; off >>= 1) s += __shfl_down(s, off);
    if ((t & 63) == 0) sred[t >> 6] = s;
    __syncthreads();
    const float mu = (sred[0] + sred[1] + sred[2] + sred[3]) * (1.0f / DMODEL);

    const float d0 = x0 - mu, d1 = x1 - mu;
    float sv = d0 * d0 + d1 * d1;
#pragma unroll
    for (int off = 32; off > 0; off >>= 1) sv += __shfl_down(sv, off);
    __syncthreads();
    if ((t & 63) == 0) sred[t >> 6] = sv;
    __syncthreads();
    const float var = (sred[0] + sred[1] + sred[2] + sred[3]) * (1.0f / DMODEL);
    const float rstd = rsqrtf(var + 1e-5f);

    const float y0 = d0 * rstd * g[t] + bb[t];
    const float y1 = d1 * rstd * g[t + 256] + bb[t + 256];
    if (outF) { outF[base + t] = y0; outF[base + t + 256] = y1; }
    if (outB) { outB[base + t] = __float2bfloat16(y0); outB[base + t + 256] = __float2bfloat16(y1); }
}

// ---------------------------------------------------------------------------
// Workspace layout (55.5 MB) — see round 5 comment.
// ---------------------------------------------------------------------------
extern "C" void kernel_launch(void* const* d_in, const int* in_sizes, int n_in,
                              void* d_out, int out_size, void* d_ws, size_t ws_size,
                              hipStream_t stream)
{
    const float* x_q       = (const float*)d_in[0];
    const float* x1        = (const float*)d_in[1];
    const float* x2        = (const float*)d_in[2];
    const float* sa_wq     = (const float*)d_in[3];
    const float* sa_bq     = (const float*)d_in[4];
    const float* sa_wk     = (const float*)d_in[5];
    const float* sa_bk     = (const float*)d_in[6];
    const float* sa_wv     = (const float*)d_in[7];
    const float* sa_bv     = (const float*)d_in[8];
    const float* ln1_g     = (const float*)d_in[9];
    const float* ln1_b     = (const float*)d_in[10];
    const float* mha_in_w  = (const float*)d_in[11];
    const float* mha_in_b  = (const float*)d_in[12];
    const float* mha_out_w = (const float*)d_in[13];
    const float* mha_out_b = (const float*)d_in[14];
    const float* ln2_g     = (const float*)d_in[15];
    const float* ln2_b     = (const float*)d_in[16];
    const float* ffn_w1    = (const float*)d_in[17];
    const float* ffn_b1    = (const float*)d_in[18];
    const float* ffn_w2    = (const float*)d_in[19];
    const float* ffn_b2    = (const float*)d_in[20];
    const float* ln3_g     = (const float*)d_in[21];
    const float* ln3_b     = (const float*)d_in[22];

    char* ws = (char*)d_ws;
    const size_t MB = 1024 * 1024;
    const size_t KB = 1024;
    bf16*  q16  = (bf16*)(ws + 0 * MB);
    bf16*  k16  = (bf16*)(ws + 4 * MB);
    bf16*  v16  = (bf16*)(ws + 8 * MB);
    bf16*  a16  = (bf16*)(ws + 12 * MB);
    float* tmp  = (float*)(ws + 16 * MB);
    bf16*  y16  = (bf16*)(ws + 24 * MB);
    bf16*  ya16 = (bf16*)(ws + 28 * MB);
    bf16*  ya2  = (bf16*)(ws + 32 * MB);
    bf16*  xq16 = (bf16*)(ws + 36 * MB);
    bf16*  x116 = (bf16*)(ws + 40 * MB);
    bf16*  x216 = (bf16*)(ws + 44 * MB);
    bf16*  w_sa_qkv = (bf16*)(ws + 48 * MB);            // 1.5 MB (3D x D contig)
    bf16*  w_in   = (bf16*)(ws + 49 * MB + 512 * KB);   // 1.5 MB
    bf16*  w_out  = (bf16*)(ws + 51 * MB);              // 0.5 MB
    bf16*  w_f1   = (bf16*)(ws + 51 * MB + 512 * KB);   // 2 MB
    bf16*  w_f2   = (bf16*)(ws + 53 * MB + 512 * KB);   // 2 MB
    bf16*  h16    = (bf16*)(ws + 0 * MB);               // aliases q..a (dead by FFN)

    const int DD = DMODEL * DMODEL;
    CvtDesc cd;
    cd.seg[0]  = { x_q,       xq16,        (NROWS * DMODEL) / 4 };
    cd.seg[1]  = { x1,        x116,        (NROWS * DMODEL) / 4 };
    cd.seg[2]  = { x2,        x216,        (NROWS * DMODEL) / 4 };
    cd.seg[3]  = { sa_wq,     w_sa_qkv,           DD / 4 };
    cd.seg[4]  = { sa_wk,     w_sa_qkv + DD,      DD / 4 };
    cd.seg[5]  = { sa_wv,     w_sa_qkv + 2 * DD,  DD / 4 };
    cd.seg[6]  = { mha_in_w,  w_in,   3 * DD / 4 };
    cd.seg[7]  = { mha_out_w, w_out,  DD / 4 };
    cd.seg[8]  = { ffn_w1,    w_f1,   (FFDIM * DMODEL) / 4 };
    cd.seg[9]  = { ffn_w2,    w_f2,   (FFDIM * DMODEL) / 4 };
    cd.seg[10] = { x_q,       xq16,   0 };
    cd.seg[11] = { x_q,       xq16,   0 };
    cvt_f32_bf16<<<dim3(64, 10), 256, 0, stream>>>(cd);

    const dim3 blk(256);
    const dim3 agrid(S_LEN / 64, BATCH * NHEAD);   // (32,16)

    Epi eQKV = {};   // self Q/K/V fused, N=1536 -> q16|k16|v16
    eQKV.outB[0] = q16; eQKV.outB[1] = k16; eQKV.outB[2] = v16;
    eQKV.bias[0] = sa_bq; eQKV.bias[1] = sa_bk; eQKV.bias[2] = sa_bv;
    eQKV.scale[0] = 0.125f; eQKV.scale[1] = 1.0f; eQKV.scale[2] = 1.0f;
    eQKV.shift = 9;

    Epi eX1 = {};    // cross1 Q|K|V fused, N=1536; A=y16 (slab0), A2=x116 (slabs 1-2)
    eX1.outB[0] = q16; eX1.outB[1] = k16; eX1.outB[2] = v16;
    eX1.bias[0] = mha_in_b; eX1.bias[1] = mha_in_b + DMODEL; eX1.bias[2] = mha_in_b + 2 * DMODEL;
    eX1.scale[0] = 0.125f; eX1.scale[1] = 1.0f; eX1.scale[2] = 1.0f;
    eX1.A2 = x116; eX1.a2slab = 1; eX1.shift = 9;

    Epi eX2 = eX1;   // cross2: A=ya16, A2=x216
    eX2.A2 = x216;

    Epi eOut = {};   // out-proj, N=512 -> tmp (fp32)
    eOut.outF[0] = tmp; eOut.bias[0] = mha_out_b; eOut.scale[0] = 1.0f; eOut.shift = 9;

    Epi eF1 = {};    // FFN1, N=2048 -> h16, relu
    eF1.outB[0] = h16; eF1.bias[0] = ffn_b1; eF1.scale[0] = 1.0f;
    eF1.shift = 11; eF1.relu = 1;

    Epi eF2 = {};    // FFN2, N=512 -> tmp (fp32)
    eF2.outF[0] = tmp; eF2.bias[0] = ffn_b2; eF2.scale[0] = 1.0f; eF2.shift = 9;

    // ---- self attention (causal, no out-proj) ----
    gemm2<64, 64><<<dim3(64, 24), blk, 0, stream>>>(xq16, w_sa_qkv, eQKV, DMODEL);
    attn_mfma<<<agrid, blk, 0, stream>>>(q16, k16, v16, tmp, nullptr, 1);
    ln_kernel<<<NROWS, blk, 0, stream>>>(tmp, x_q, nullptr, ln1_g, ln1_b, nullptr, y16);

    // ---- cross attention 1: q from y, k/v from x1 (one fused GEMM) ----
    gemm2<64, 64><<<dim3(64, 24), blk, 0, stream>>>(y16, w_in, eX1, DMODEL);
    attn_mfma<<<agrid, blk, 0, stream>>>(q16, k16, v16, nullptr, a16, 0);
    gemm2<64, 64><<<dim3(64, 8), blk, 0, stream>>>(a16, w_out, eOut, DMODEL);
    ln_kernel<<<NROWS, blk, 0, stream>>>(tmp, nullptr, y16, ln2_g, ln2_b, nullptr, ya16);

    // ---- cross attention 2: q from yattn, k/v from x2 ----
    gemm2<64, 64><<<dim3(64, 24), blk, 0, stream>>>(ya16, w_in, eX2, DMODEL);
    attn_mfma<<<agrid, blk, 0, stream>>>(q16, k16, v16, nullptr, a16, 0);
    gemm2<64, 64><<<dim3(64, 8), blk, 0, stream>>>(a16, w_out, eOut, DMODEL);
    ln_kernel<<<NROWS, blk, 0, stream>>>(tmp, nullptr, ya16, ln2_g, ln2_b, nullptr, ya2);

    // ---- FFN ----
    gemm2<128, 128><<<dim3(32, 16), blk, 0, stream>>>(ya2, w_f1, eF1, DMODEL);
    gemm2<64, 64><<<dim3(64, 8), blk, 0, stream>>>(h16, w_f2, eF2, FFDIM);
    ln_kernel<<<NROWS, blk, 0, stream>>>(tmp, nullptr, ya2, ln3_g, ln3_b, (float*)d_out, nullptr);
}